// Round 6
// baseline (318.022 us; speedup 1.0000x reference)
//
#include <hip/hip_runtime.h>
#include <math.h>

#define IN_CAPS 512
#define QN      512
#define IN_DIM  768
#define NCAPS   64
#define DCAPS   16
#define CD      1024   // NCAPS*DCAPS

// tanh via depth-3 continued fraction (|x|<=~1.05, err ~4e-6)
__device__ __forceinline__ float tanh_pade(float x){
  const float x2 = x*x;
  const float num = fmaf(x2, x2 + 105.0f, 945.0f);
  const float den = fmaf(x2, fmaf(x2, 15.0f, 420.0f), 945.0f);
  return x * num * __frcp_rn(den);
}

template<int CTRL>
__device__ __forceinline__ float dpp_add(float v){
  int r = __builtin_amdgcn_update_dpp(0, __float_as_int(v), CTRL, 0xF, 0xF, true);
  return v + __int_as_float(r);
}

// full 64-lane sum -> uniform scalar (pure VALU DPP chain + readlane, no LDS ops)
__device__ __forceinline__ float wave_sum64_all(float v){
  v = dpp_add<0xB1>(v);    // quad_perm xor1
  v = dpp_add<0x4E>(v);    // quad_perm xor2
  v = dpp_add<0x141>(v);   // row_half_mirror
  v = dpp_add<0x140>(v);   // row_mirror  -> each 16-row holds its row sum
  v = dpp_add<0x142>(v);   // row_bcast15 -> rows 1,3 hold pair sums
  v = dpp_add<0x143>(v);   // row_bcast31 -> lanes 48..63 hold total
  return __int_as_float(__builtin_amdgcn_readlane(__float_as_int(v), 63));
}

#define LD16(dst, ptr) { const float4* _p=(const float4*)(ptr); \
  float4 _a=_p[0], _b=_p[1], _c=_p[2], _d=_p[3]; \
  dst[0]=_a.x; dst[1]=_a.y; dst[2]=_a.z; dst[3]=_a.w; \
  dst[4]=_b.x; dst[5]=_b.y; dst[6]=_b.z; dst[7]=_b.w; \
  dst[8]=_c.x; dst[9]=_c.y; dst[10]=_c.z; dst[11]=_c.w; \
  dst[12]=_d.x; dst[13]=_d.y; dst[14]=_d.z; dst[15]=_d.w; }

#define ST16(ptr, src) { float4* _p=(float4*)(ptr); \
  _p[0]=make_float4(src[0],src[1],src[2],src[3]); \
  _p[1]=make_float4(src[4],src[5],src[6],src[7]); \
  _p[2]=make_float4(src[8],src[9],src[10],src[11]); \
  _p[3]=make_float4(src[12],src[13],src[14],src[15]); }

// 2-way-split dot of two 16-vecs
#define DOT16(res, x, y) { float _e=0.f,_o=0.f; \
  _Pragma("unroll") for (int _d=0;_d<16;_d+=2){ _e += x[_d]*y[_d]; _o += x[_d+1]*y[_d+1]; } \
  res = _e+_o; }

// compute centered hat_q fragment + rsqrt norm for lane's capsule
#define QPROLOGUE() { \
  float qc_[16]; \
  LD16(qc_, hat + (size_t)(IN_CAPS + q)*CD + c*16); \
  float s_=0.f; \
  _Pragma("unroll") for (int d=0;d<16;d++) s_ += qc_[d]; \
  const float mean_ = s_*(1.0f/16.0f); \
  float n2_=0.f; \
  _Pragma("unroll") for (int d=0;d<16;d++){ qcc1[d]=qc_[d]-mean_; n2_ += qcc1[d]*qcc1[d]; } \
  s1 = __frsqrt_rn(n2_ + 1e-12f); }

// ---------------- K0: hat = [m;q] @ W_w + W_b ----------------
__global__ __launch_bounds__(256) void gemm_hat(const float* __restrict__ m,
                                                const float* __restrict__ q,
                                                const float* __restrict__ Ww,
                                                const float* __restrict__ Wb,
                                                float* __restrict__ hat)
{
  __shared__ float As[16][65];
  __shared__ float Bs[16][65];
  const int tid = threadIdx.x;
  const int bm = blockIdx.y, bn = blockIdx.x;
  const int tx = tid & 15, ty = tid >> 4;

  float acc[4][4];
  #pragma unroll
  for (int a=0;a<4;a++)
    #pragma unroll
    for (int b=0;b<4;b++) acc[a][b]=0.0f;

  const int r  = tid >> 2;
  const int kk = (tid & 3) << 2;
  const int row = bm*64 + r;
  const float* srcA = (row < IN_CAPS) ? (m + row*IN_DIM) : (q + (row-IN_CAPS)*IN_DIM);
  const int krow = tid >> 4;
  const int cc   = (tid & 15) << 2;

  for (int k0=0; k0<IN_DIM; k0+=16){
    float4 av = *(const float4*)(srcA + k0 + kk);
    As[kk+0][r]=av.x; As[kk+1][r]=av.y; As[kk+2][r]=av.z; As[kk+3][r]=av.w;
    float4 bv = *(const float4*)(Ww + (size_t)(k0+krow)*CD + bn*64 + cc);
    Bs[krow][cc+0]=bv.x; Bs[krow][cc+1]=bv.y; Bs[krow][cc+2]=bv.z; Bs[krow][cc+3]=bv.w;
    __syncthreads();
    #pragma unroll
    for (int k=0;k<16;k++){
      float a[4], b[4];
      #pragma unroll
      for (int j=0;j<4;j++) a[j] = As[k][ty*4+j];
      #pragma unroll
      for (int j=0;j<4;j++) b[j] = Bs[k][tx*4+j];
      #pragma unroll
      for (int ii=0;ii<4;ii++)
        #pragma unroll
        for (int jj=0;jj<4;jj++) acc[ii][jj] += a[ii]*b[jj];
    }
    __syncthreads();
  }
  #pragma unroll
  for (int ii=0;ii<4;ii++){
    const int orow = bm*64 + ty*4 + ii;
    #pragma unroll
    for (int jj=0;jj<4;jj++){
      const int ocol = bn*64 + tx*4 + jj;
      hat[(size_t)orow*CD + ocol] = acc[ii][jj] + Wb[ocol];
    }
  }
}

// ---------------- K1: per-(i,c) stats ----------------
__global__ __launch_bounds__(256) void stats_kernel(const float* __restrict__ hat,
                                                    float2* __restrict__ rs)
{
  const int t = blockIdx.x*256 + threadIdx.x;
  const int i = t >> 6, c = t & 63;
  float v[16];
  LD16(v, hat + (size_t)i*CD + c*16);
  float s=0.f;
  #pragma unroll
  for (int d=0;d<16;d++) s += v[d];
  const float mean = s*(1.0f/16.0f);
  float n2=0.f;
  #pragma unroll
  for (int d=0;d<16;d++){ float x=v[d]-mean; n2+=x*x; }
  rs[t] = make_float2(__frsqrt_rn(n2 + 1e-12f), s);
}

// ---------------- P1: partial pass 1 (barrier-free, one wave per (q,chunk)) ----------------
__global__ __launch_bounds__(256) void pass1_kernel(const float* __restrict__ hat,
                                                    const float2* __restrict__ rs_g,
                                                    float* __restrict__ part,
                                                    int ilen, int cshift)
{
  const int tid = threadIdx.x;
  const int gw  = blockIdx.x*4 + (tid >> 6);
  const int q   = gw >> cshift;
  const int ch  = gw - (q << cshift);
  const int c   = tid & 63;

  float qcc1[16], s1;
  QPROLOGUE();

  float acc[16];
  #pragma unroll
  for (int d=0;d<16;d++) acc[d]=0.f;

  const int i0 = ch*ilen;
  const float* mp = hat + (size_t)i0*CD + c*16;
  const float2* rp = rs_g + i0*64 + c;
  for (int i=0;i<ilen;i+=2, mp+=2*CD, rp+=128){
    float ma[16], mb[16];
    LD16(ma, mp); LD16(mb, mp+CD);
    const float ra = rp[0].x, rb = rp[64].x;
    float nA, nB;
    DOT16(nA, ma, qcc1);
    DOT16(nB, mb, qcc1);
    const float wA = 0.015625f + tanh_pade(nA*ra*s1);
    const float wB = 0.015625f + tanh_pade(nB*rb*s1);
    #pragma unroll
    for (int d=0;d<16;d++){ acc[d] += wA*ma[d]; acc[d] += wB*mb[d]; }
  }
  ST16(part + ((size_t)gw*64 + c)*16, acc);
}

// ---------------- R1: reduce -> v1, aux1=(s2, mv1) ----------------
__global__ __launch_bounds__(64) void reduce1_kernel(const float* __restrict__ hat,
                                                     const float* __restrict__ part,
                                                     float* __restrict__ v1g,
                                                     float2* __restrict__ aux1,
                                                     int nchunk)
{
  const int q = blockIdx.x, c = threadIdx.x;
  float hv[16];
  #pragma unroll
  for (int d=0;d<16;d++) hv[d]=0.f;
  const float* pp = part + ((size_t)q*nchunk*64 + c)*16;
  for (int ch=0; ch<nchunk; ch++, pp += 1024){
    float t[16]; LD16(t, pp);
    #pragma unroll
    for (int d=0;d<16;d++) hv[d]+=t[d];
  }
  float n2=0.f;
  #pragma unroll
  for (int d=0;d<16;d++) n2 += hv[d]*hv[d];
  const float sc = n2 / ((1.0f+n2)*sqrtf(n2+1e-8f));
  float v1[16]; float sv=0.f;
  #pragma unroll
  for (int d=0;d<16;d++){ v1[d]=hv[d]*sc; sv+=v1[d]; }
  ST16(v1g + ((size_t)q*64 + c)*16, v1);
  float qc[16]; LD16(qc, hat + (size_t)(IN_CAPS+q)*CD + c*16);
  float s=0.f, ss=0.f;
  #pragma unroll
  for (int d=0;d<16;d++){ const float t2 = 0.5f*(qc[d]+v1[d]); s+=t2; ss+=t2*t2; }
  const float mean = s*(1.0f/16.0f);
  aux1[q*64+c] = make_float2(__frsqrt_rn(ss - 16.0f*mean*mean + 1e-12f), sv*(1.0f/16.0f));
}

// ---------------- P2: partial pass 2 ----------------
__global__ __launch_bounds__(256) void pass2_kernel(const float* __restrict__ hat,
                                                    const float2* __restrict__ rs_g,
                                                    const float* __restrict__ v1g,
                                                    const float2* __restrict__ aux1,
                                                    float* __restrict__ part,
                                                    int ilen, int cshift)
{
  const int tid = threadIdx.x;
  const int gw  = blockIdx.x*4 + (tid >> 6);
  const int q   = gw >> cshift;
  const int ch  = gw - (q << cshift);
  const int c   = tid & 63;

  float qcc1[16], s1;
  QPROLOGUE();
  float v1[16];
  LD16(v1, v1g + ((size_t)q*64 + c)*16);
  const float2 a1 = aux1[q*64+c];
  const float s2 = a1.x, mv1 = a1.y;

  float acc[16];
  #pragma unroll
  for (int d=0;d<16;d++) acc[d]=0.f;

  const int i0 = ch*ilen;
  const float* mp = hat + (size_t)i0*CD + c*16;
  const float2* rp = rs_g + i0*64 + c;
  for (int i=0;i<ilen;i+=2, mp+=2*CD, rp+=128){
    float ma[16], mb[16];
    LD16(ma, mp); LD16(mb, mp+CD);
    const float2 ra = rp[0], rb = rp[64];
    float n1A, cvA, n1B, cvB;
    DOT16(n1A, ma, qcc1); DOT16(cvA, ma, v1);
    DOT16(n1B, mb, qcc1); DOT16(cvB, mb, v1);
    const float p1A = tanh_pade(n1A*ra.x*s1);
    const float p2A = tanh_pade(0.5f*(n1A + cvA - mv1*ra.y)*ra.x*s2);
    const float p1B = tanh_pade(n1B*rb.x*s1);
    const float p2B = tanh_pade(0.5f*(n1B + cvB - mv1*rb.y)*rb.x*s2);
    const float eA = __expf(p1A*cvA);
    const float eB = __expf(p1B*cvB);
    const float SA = wave_sum64_all(eA);
    const float SB = wave_sum64_all(eB);
    const float wA = eA*__frcp_rn(SA) + p2A;
    const float wB = eB*__frcp_rn(SB) + p2B;
    #pragma unroll
    for (int d=0;d<16;d++){ acc[d] += wA*ma[d]; acc[d] += wB*mb[d]; }
  }
  ST16(part + ((size_t)gw*64 + c)*16, acc);
}

// ---------------- R2: reduce -> v2, aux2=(s3, mv2) ----------------
__global__ __launch_bounds__(64) void reduce2_kernel(const float* __restrict__ hat,
                                                     const float* __restrict__ part,
                                                     const float* __restrict__ v1g,
                                                     float* __restrict__ v2g,
                                                     float2* __restrict__ aux2,
                                                     int nchunk)
{
  const int q = blockIdx.x, c = threadIdx.x;
  float hv[16];
  #pragma unroll
  for (int d=0;d<16;d++) hv[d]=0.f;
  const float* pp = part + ((size_t)q*nchunk*64 + c)*16;
  for (int ch=0; ch<nchunk; ch++, pp += 1024){
    float t[16]; LD16(t, pp);
    #pragma unroll
    for (int d=0;d<16;d++) hv[d]+=t[d];
  }
  float n2=0.f;
  #pragma unroll
  for (int d=0;d<16;d++) n2 += hv[d]*hv[d];
  const float sc = n2 / ((1.0f+n2)*sqrtf(n2+1e-8f));
  float v2[16]; float sv=0.f;
  #pragma unroll
  for (int d=0;d<16;d++){ v2[d]=hv[d]*sc; sv+=v2[d]; }
  ST16(v2g + ((size_t)q*64 + c)*16, v2);
  float qc[16];  LD16(qc, hat + (size_t)(IN_CAPS+q)*CD + c*16);
  float v1[16];  LD16(v1, v1g + ((size_t)q*64 + c)*16);
  float s=0.f, ss=0.f;
  #pragma unroll
  for (int d=0;d<16;d++){
    const float t3 = 0.25f*qc[d] + 0.25f*v1[d] + 0.5f*v2[d];   // q_cur3
    s+=t3; ss+=t3*t3;
  }
  const float mean = s*(1.0f/16.0f);
  aux2[q*64+c] = make_float2(__frsqrt_rn(ss - 16.0f*mean*mean + 1e-12f), sv*(1.0f/16.0f));
}

// ---------------- P3: partial pass 3 ----------------
__global__ __launch_bounds__(256) void pass3_kernel(const float* __restrict__ hat,
                                                    const float2* __restrict__ rs_g,
                                                    const float* __restrict__ v1g,
                                                    const float* __restrict__ v2g,
                                                    const float2* __restrict__ aux1,
                                                    const float2* __restrict__ aux2,
                                                    float* __restrict__ part,
                                                    int ilen, int cshift)
{
  const int tid = threadIdx.x;
  const int gw  = blockIdx.x*4 + (tid >> 6);
  const int q   = gw >> cshift;
  const int ch  = gw - (q << cshift);
  const int c   = tid & 63;

  float qcc1[16], s1;
  QPROLOGUE();
  float v1[16], v2[16];
  LD16(v1, v1g + ((size_t)q*64 + c)*16);
  LD16(v2, v2g + ((size_t)q*64 + c)*16);
  const float2 a1 = aux1[q*64+c];
  const float2 a2 = aux2[q*64+c];
  const float s2 = a1.x, mv1 = a1.y, s3 = a2.x, mv2 = a2.y;

  float acc[16];
  #pragma unroll
  for (int d=0;d<16;d++) acc[d]=0.f;

  const int i0 = ch*ilen;
  const float* mp = hat + (size_t)i0*CD + c*16;
  const float2* rp = rs_g + i0*64 + c;
  for (int i=0;i<ilen;i+=2, mp+=2*CD, rp+=128){
    float ma[16], mb[16];
    LD16(ma, mp); LD16(mb, mp+CD);
    const float2 ra = rp[0], rb = rp[64];
    float n1A, cvA, cwA, n1B, cvB, cwB;
    DOT16(n1A, ma, qcc1); DOT16(cvA, ma, v1); DOT16(cwA, ma, v2);
    DOT16(n1B, mb, qcc1); DOT16(cvB, mb, v1); DOT16(cwB, mb, v2);
    const float p1A = tanh_pade(n1A*ra.x*s1);
    const float n2A = 0.5f*(n1A + cvA - mv1*ra.y);
    const float p2A = tanh_pade(n2A*ra.x*s2);
    const float p3A = tanh_pade(0.5f*(n2A + cwA - mv2*ra.y)*ra.x*s3);
    const float p1B = tanh_pade(n1B*rb.x*s1);
    const float n2B = 0.5f*(n1B + cvB - mv1*rb.y);
    const float p2B = tanh_pade(n2B*rb.x*s2);
    const float p3B = tanh_pade(0.5f*(n2B + cwB - mv2*rb.y)*rb.x*s3);
    const float eA = __expf(p1A*cvA + p2A*cwA);
    const float eB = __expf(p1B*cvB + p2B*cwB);
    const float SA = wave_sum64_all(eA);
    const float SB = wave_sum64_all(eB);
    const float wA = eA*__frcp_rn(SA) + p3A;
    const float wB = eB*__frcp_rn(SB) + p3B;
    #pragma unroll
    for (int d=0;d<16;d++){ acc[d] += wA*ma[d]; acc[d] += wB*mb[d]; }
  }
  ST16(part + ((size_t)gw*64 + c)*16, acc);
}

// ---------------- R3: reduce -> squash -> out ----------------
__global__ __launch_bounds__(64) void reduce3_kernel(const float* __restrict__ part,
                                                     float* __restrict__ out,
                                                     int nchunk)
{
  const int q = blockIdx.x, c = threadIdx.x;
  float hv[16];
  #pragma unroll
  for (int d=0;d<16;d++) hv[d]=0.f;
  const float* pp = part + ((size_t)q*nchunk*64 + c)*16;
  for (int ch=0; ch<nchunk; ch++, pp += 1024){
    float t[16]; LD16(t, pp);
    #pragma unroll
    for (int d=0;d<16;d++) hv[d]+=t[d];
  }
  float n2=0.f;
  #pragma unroll
  for (int d=0;d<16;d++) n2 += hv[d]*hv[d];
  const float sc = n2 / ((1.0f+n2)*sqrtf(n2+1e-8f));
  float o[16];
  #pragma unroll
  for (int d=0;d<16;d++) o[d] = hv[d]*sc;
  ST16(out + (size_t)q*CD + c*16, o);
}

extern "C" void kernel_launch(void* const* d_in, const int* in_sizes, int n_in,
                              void* d_out, int out_size, void* d_ws, size_t ws_size,
                              hipStream_t stream)
{
  const float* m  = (const float*)d_in[0];
  const float* q  = (const float*)d_in[1];
  const float* Ww = (const float*)d_in[2];
  const float* Wb = (const float*)d_in[3];
  float* out = (float*)d_out;

  char* ws = (char*)d_ws;
  float*  hat  = (float*) (ws + 0);          // 4,194,304 B
  float2* rs   = (float2*)(ws + 4194304);    //   262,144 B
  float*  v1g  = (float*) (ws + 4456448);    // 2,097,152 B
  float*  v2g  = (float*) (ws + 6553600);    // 2,097,152 B
  float2* aux1 = (float2*)(ws + 8650752);    //   262,144 B
  float2* aux2 = (float2*)(ws + 8912896);    //   262,144 B
  float*  part = (float*) (ws + 9175040);    // nchunk * 2,097,152 B

  // pick largest nchunk whose partial buffer fits the workspace
  int nchunk = 16, cshift = 4;
  while (nchunk > 1 && 9175040ull + (size_t)nchunk*2097152ull > ws_size){ nchunk >>= 1; cshift--; }
  const int ilen = 512 / nchunk;
  const int pblocks = 512*nchunk/4;   // 4 waves per 256-thread block

  dim3 g0(16,16);
  gemm_hat<<<g0, 256, 0, stream>>>(m, q, Ww, Wb, hat);
  stats_kernel<<<128, 256, 0, stream>>>(hat, rs);
  pass1_kernel<<<pblocks, 256, 0, stream>>>(hat, rs, part, ilen, cshift);
  reduce1_kernel<<<512, 64, 0, stream>>>(hat, part, v1g, aux1, nchunk);
  pass2_kernel<<<pblocks, 256, 0, stream>>>(hat, rs, v1g, aux1, part, ilen, cshift);
  reduce2_kernel<<<512, 64, 0, stream>>>(hat, part, v1g, v2g, aux2, nchunk);
  pass3_kernel<<<pblocks, 256, 0, stream>>>(hat, rs, v1g, v2g, aux1, aux2, part, ilen, cshift);
  reduce3_kernel<<<512, 64, 0, stream>>>(part, out, nchunk);
}

// Round 7
// 317.700 us; speedup vs baseline: 1.0010x; 1.0010x over previous
//
#include <hip/hip_runtime.h>
#include <math.h>

#define IN_CAPS 512
#define QN      512
#define IN_DIM  768
#define NCAPS   64
#define DCAPS   16
#define CD      1024   // NCAPS*DCAPS

// tanh via depth-3 continued fraction (|x|<=~1.05, err ~4e-6)
__device__ __forceinline__ float tanh_pade(float x){
  const float x2 = x*x;
  const float num = fmaf(x2, x2 + 105.0f, 945.0f);
  const float den = fmaf(x2, fmaf(x2, 15.0f, 420.0f), 945.0f);
  return x * num * __frcp_rn(den);
}

template<int CTRL>
__device__ __forceinline__ float dpp_add(float v){
  int r = __builtin_amdgcn_update_dpp(0, __float_as_int(v), CTRL, 0xF, 0xF, true);
  return v + __int_as_float(r);
}

// full 64-lane sum -> uniform scalar (pure VALU DPP chain + readlane)
__device__ __forceinline__ float wave_sum64_all(float v){
  v = dpp_add<0xB1>(v);    // quad_perm xor1
  v = dpp_add<0x4E>(v);    // quad_perm xor2
  v = dpp_add<0x141>(v);   // row_half_mirror
  v = dpp_add<0x140>(v);   // row_mirror  -> each 16-row holds its row sum
  v = dpp_add<0x142>(v);   // row_bcast15
  v = dpp_add<0x143>(v);   // row_bcast31 -> lanes 48..63 hold total
  return __int_as_float(__builtin_amdgcn_readlane(__float_as_int(v), 63));
}

#define LD16(dst, ptr) { const float4* _p=(const float4*)(ptr); \
  float4 _a=_p[0], _b=_p[1], _c=_p[2], _d=_p[3]; \
  dst[0]=_a.x; dst[1]=_a.y; dst[2]=_a.z; dst[3]=_a.w; \
  dst[4]=_b.x; dst[5]=_b.y; dst[6]=_b.z; dst[7]=_b.w; \
  dst[8]=_c.x; dst[9]=_c.y; dst[10]=_c.z; dst[11]=_c.w; \
  dst[12]=_d.x; dst[13]=_d.y; dst[14]=_d.z; dst[15]=_d.w; }

#define ST16(ptr, src) { float4* _p=(float4*)(ptr); \
  _p[0]=make_float4(src[0],src[1],src[2],src[3]); \
  _p[1]=make_float4(src[4],src[5],src[6],src[7]); \
  _p[2]=make_float4(src[8],src[9],src[10],src[11]); \
  _p[3]=make_float4(src[12],src[13],src[14],src[15]); }

// 2-way-split dot of two 16-vecs
#define DOT16(res, x, y) { float _e=0.f,_o=0.f; \
  _Pragma("unroll") for (int _d=0;_d<16;_d+=2){ _e += x[_d]*y[_d]; _o += x[_d+1]*y[_d+1]; } \
  res = _e+_o; }

// centered hat_q fragment + rsqrt norm for lane's capsule
#define QPROLOGUE() { \
  float qc_[16]; \
  LD16(qc_, hat + (size_t)(IN_CAPS + q)*CD + c*16); \
  float s_=0.f; \
  _Pragma("unroll") for (int d=0;d<16;d++) s_ += qc_[d]; \
  const float mean_ = s_*(1.0f/16.0f); \
  float n2_=0.f; \
  _Pragma("unroll") for (int d=0;d<16;d++){ qcc1[d]=qc_[d]-mean_; n2_ += qcc1[d]*qcc1[d]; } \
  s1 = __frsqrt_rn(n2_ + 1e-12f); }

// block decomposition: 4 waves = 4 consecutive q's sharing one i-chunk (L1 reuse)
#define QCH_DECODE() \
  const int tid = threadIdx.x; \
  const int ch  = blockIdx.x & (nch-1); \
  const int qg  = blockIdx.x >> cshift; \
  const int q   = qg*4 + (tid >> 6); \
  const int c   = tid & 63;

// ---------------- K0: hat = [m;q] @ W_w + W_b ----------------
__global__ __launch_bounds__(256) void gemm_hat(const float* __restrict__ m,
                                                const float* __restrict__ q,
                                                const float* __restrict__ Ww,
                                                const float* __restrict__ Wb,
                                                float* __restrict__ hat)
{
  __shared__ float As[16][65];
  __shared__ float Bs[16][65];
  const int tid = threadIdx.x;
  const int bm = blockIdx.y, bn = blockIdx.x;
  const int tx = tid & 15, ty = tid >> 4;

  float acc[4][4];
  #pragma unroll
  for (int a=0;a<4;a++)
    #pragma unroll
    for (int b=0;b<4;b++) acc[a][b]=0.0f;

  const int r  = tid >> 2;
  const int kk = (tid & 3) << 2;
  const int row = bm*64 + r;
  const float* srcA = (row < IN_CAPS) ? (m + row*IN_DIM) : (q + (row-IN_CAPS)*IN_DIM);
  const int krow = tid >> 4;
  const int cc   = (tid & 15) << 2;

  for (int k0=0; k0<IN_DIM; k0+=16){
    float4 av = *(const float4*)(srcA + k0 + kk);
    As[kk+0][r]=av.x; As[kk+1][r]=av.y; As[kk+2][r]=av.z; As[kk+3][r]=av.w;
    float4 bv = *(const float4*)(Ww + (size_t)(k0+krow)*CD + bn*64 + cc);
    Bs[krow][cc+0]=bv.x; Bs[krow][cc+1]=bv.y; Bs[krow][cc+2]=bv.z; Bs[krow][cc+3]=bv.w;
    __syncthreads();
    #pragma unroll
    for (int k=0;k<16;k++){
      float a[4], b[4];
      #pragma unroll
      for (int j=0;j<4;j++) a[j] = As[k][ty*4+j];
      #pragma unroll
      for (int j=0;j<4;j++) b[j] = Bs[k][tx*4+j];
      #pragma unroll
      for (int ii=0;ii<4;ii++)
        #pragma unroll
        for (int jj=0;jj<4;jj++) acc[ii][jj] += a[ii]*b[jj];
    }
    __syncthreads();
  }
  #pragma unroll
  for (int ii=0;ii<4;ii++){
    const int orow = bm*64 + ty*4 + ii;
    #pragma unroll
    for (int jj=0;jj<4;jj++){
      const int ocol = bn*64 + tx*4 + jj;
      hat[(size_t)orow*CD + ocol] = acc[ii][jj] + Wb[ocol];
    }
  }
}

// ---------------- K1: per-(i,c) stats ----------------
__global__ __launch_bounds__(256) void stats_kernel(const float* __restrict__ hat,
                                                    float2* __restrict__ rs)
{
  const int t = blockIdx.x*256 + threadIdx.x;
  const int i = t >> 6, c = t & 63;
  float v[16];
  LD16(v, hat + (size_t)i*CD + c*16);
  float s=0.f;
  #pragma unroll
  for (int d=0;d<16;d++) s += v[d];
  const float mean = s*(1.0f/16.0f);
  float n2=0.f;
  #pragma unroll
  for (int d=0;d<16;d++){ float x=v[d]-mean; n2+=x*x; }
  rs[t] = make_float2(__frsqrt_rn(n2 + 1e-12f), s);
}

// ---------------- P1: partial pass 1 ----------------
__global__ __launch_bounds__(256) void pass1_kernel(const float* __restrict__ hat,
                                                    const float2* __restrict__ rs_g,
                                                    float* __restrict__ part,
                                                    int ilen, int nch, int cshift)
{
  QCH_DECODE();
  float qcc1[16], s1;
  QPROLOGUE();

  float acc[16];
  #pragma unroll
  for (int d=0;d<16;d++) acc[d]=0.f;

  const int i0 = ch*ilen;
  const float* mp = hat + (size_t)i0*CD + c*16;
  const float2* rp = rs_g + i0*64 + c;
  for (int i=0;i<ilen;i+=2, mp+=2*CD, rp+=128){
    float ma[16], mb[16];
    LD16(ma, mp); LD16(mb, mp+CD);
    const float ra = rp[0].x, rb = rp[64].x;
    float nA, nB;
    DOT16(nA, ma, qcc1);
    DOT16(nB, mb, qcc1);
    const float wA = 0.015625f + tanh_pade(nA*ra*s1);
    const float wB = 0.015625f + tanh_pade(nB*rb*s1);
    #pragma unroll
    for (int d=0;d<16;d++){ acc[d] += wA*ma[d]; acc[d] += wB*mb[d]; }
  }
  ST16(part + (((size_t)(q<<cshift) + ch)*64 + c)*16, acc);
}

// ---------------- R1: reduce -> v1, aux1=(s2, mv1) ----------------
__global__ __launch_bounds__(64) void reduce1_kernel(const float* __restrict__ hat,
                                                     const float* __restrict__ part,
                                                     float* __restrict__ v1g,
                                                     float2* __restrict__ aux1,
                                                     int nchunk)
{
  const int q = blockIdx.x, c = threadIdx.x;
  float hv[16];
  #pragma unroll
  for (int d=0;d<16;d++) hv[d]=0.f;
  const float* pp = part + ((size_t)q*nchunk*64 + c)*16;
  for (int ch=0; ch<nchunk; ch++, pp += 1024){
    float t[16]; LD16(t, pp);
    #pragma unroll
    for (int d=0;d<16;d++) hv[d]+=t[d];
  }
  float n2=0.f;
  #pragma unroll
  for (int d=0;d<16;d++) n2 += hv[d]*hv[d];
  const float sc = n2 / ((1.0f+n2)*sqrtf(n2+1e-8f));
  float v1[16]; float sv=0.f;
  #pragma unroll
  for (int d=0;d<16;d++){ v1[d]=hv[d]*sc; sv+=v1[d]; }
  ST16(v1g + ((size_t)q*64 + c)*16, v1);
  float qc[16]; LD16(qc, hat + (size_t)(IN_CAPS+q)*CD + c*16);
  float s=0.f, ss=0.f;
  #pragma unroll
  for (int d=0;d<16;d++){ const float t2 = 0.5f*(qc[d]+v1[d]); s+=t2; ss+=t2*t2; }
  const float mean = s*(1.0f/16.0f);
  aux1[q*64+c] = make_float2(__frsqrt_rn(ss - 16.0f*mean*mean + 1e-12f), sv*(1.0f/16.0f));
}

// ---------------- P2: partial pass 2 ----------------
__global__ __launch_bounds__(256) void pass2_kernel(const float* __restrict__ hat,
                                                    const float2* __restrict__ rs_g,
                                                    const float* __restrict__ v1g,
                                                    const float2* __restrict__ aux1,
                                                    float* __restrict__ part,
                                                    int ilen, int nch, int cshift)
{
  QCH_DECODE();
  float qcc1[16], s1;
  QPROLOGUE();
  float v1[16];
  LD16(v1, v1g + ((size_t)q*64 + c)*16);
  const float2 a1 = aux1[q*64+c];
  const float s2 = a1.x, mv1 = a1.y;

  float acc[16];
  #pragma unroll
  for (int d=0;d<16;d++) acc[d]=0.f;

  const int i0 = ch*ilen;
  const float* mp = hat + (size_t)i0*CD + c*16;
  const float2* rp = rs_g + i0*64 + c;
  for (int i=0;i<ilen;i+=2, mp+=2*CD, rp+=128){
    float ma[16], mb[16];
    LD16(ma, mp); LD16(mb, mp+CD);
    const float2 ra = rp[0], rb = rp[64];
    float n1A, cvA, n1B, cvB;
    DOT16(n1A, ma, qcc1); DOT16(cvA, ma, v1);
    DOT16(n1B, mb, qcc1); DOT16(cvB, mb, v1);
    const float p1A = tanh_pade(n1A*ra.x*s1);
    const float p2A = tanh_pade(0.5f*(n1A + cvA - mv1*ra.y)*ra.x*s2);
    const float p1B = tanh_pade(n1B*rb.x*s1);
    const float p2B = tanh_pade(0.5f*(n1B + cvB - mv1*rb.y)*rb.x*s2);
    const float eA = __expf(p1A*cvA);
    const float eB = __expf(p1B*cvB);
    const float SA = wave_sum64_all(eA);
    const float SB = wave_sum64_all(eB);
    const float wA = eA*__frcp_rn(SA) + p2A;
    const float wB = eB*__frcp_rn(SB) + p2B;
    #pragma unroll
    for (int d=0;d<16;d++){ acc[d] += wA*ma[d]; acc[d] += wB*mb[d]; }
  }
  ST16(part + (((size_t)(q<<cshift) + ch)*64 + c)*16, acc);
}

// ---------------- R2: reduce -> v2, aux2=(s3, mv2) ----------------
__global__ __launch_bounds__(64) void reduce2_kernel(const float* __restrict__ hat,
                                                     const float* __restrict__ part,
                                                     const float* __restrict__ v1g,
                                                     float* __restrict__ v2g,
                                                     float2* __restrict__ aux2,
                                                     int nchunk)
{
  const int q = blockIdx.x, c = threadIdx.x;
  float hv[16];
  #pragma unroll
  for (int d=0;d<16;d++) hv[d]=0.f;
  const float* pp = part + ((size_t)q*nchunk*64 + c)*16;
  for (int ch=0; ch<nchunk; ch++, pp += 1024){
    float t[16]; LD16(t, pp);
    #pragma unroll
    for (int d=0;d<16;d++) hv[d]+=t[d];
  }
  float n2=0.f;
  #pragma unroll
  for (int d=0;d<16;d++) n2 += hv[d]*hv[d];
  const float sc = n2 / ((1.0f+n2)*sqrtf(n2+1e-8f));
  float v2[16]; float sv=0.f;
  #pragma unroll
  for (int d=0;d<16;d++){ v2[d]=hv[d]*sc; sv+=v2[d]; }
  ST16(v2g + ((size_t)q*64 + c)*16, v2);
  float qc[16];  LD16(qc, hat + (size_t)(IN_CAPS+q)*CD + c*16);
  float v1[16];  LD16(v1, v1g + ((size_t)q*64 + c)*16);
  float s=0.f, ss=0.f;
  #pragma unroll
  for (int d=0;d<16;d++){
    const float t3 = 0.25f*qc[d] + 0.25f*v1[d] + 0.5f*v2[d];   // q_cur3
    s+=t3; ss+=t3*t3;
  }
  const float mean = s*(1.0f/16.0f);
  aux2[q*64+c] = make_float2(__frsqrt_rn(ss - 16.0f*mean*mean + 1e-12f), sv*(1.0f/16.0f));
}

// ---------------- P3: partial pass 3 ----------------
__global__ __launch_bounds__(256) void pass3_kernel(const float* __restrict__ hat,
                                                    const float2* __restrict__ rs_g,
                                                    const float* __restrict__ v1g,
                                                    const float* __restrict__ v2g,
                                                    const float2* __restrict__ aux1,
                                                    const float2* __restrict__ aux2,
                                                    float* __restrict__ part,
                                                    int ilen, int nch, int cshift)
{
  QCH_DECODE();
  float qcc1[16], s1;
  QPROLOGUE();
  float v1[16], v2[16];
  LD16(v1, v1g + ((size_t)q*64 + c)*16);
  LD16(v2, v2g + ((size_t)q*64 + c)*16);
  const float2 a1 = aux1[q*64+c];
  const float2 a2 = aux2[q*64+c];
  const float s2 = a1.x, mv1 = a1.y, s3 = a2.x, mv2 = a2.y;

  float acc[16];
  #pragma unroll
  for (int d=0;d<16;d++) acc[d]=0.f;

  const int i0 = ch*ilen;
  const float* mp = hat + (size_t)i0*CD + c*16;
  const float2* rp = rs_g + i0*64 + c;
  for (int i=0;i<ilen;i+=2, mp+=2*CD, rp+=128){
    float ma[16], mb[16];
    LD16(ma, mp); LD16(mb, mp+CD);
    const float2 ra = rp[0], rb = rp[64];
    float n1A, cvA, cwA, n1B, cvB, cwB;
    DOT16(n1A, ma, qcc1); DOT16(cvA, ma, v1); DOT16(cwA, ma, v2);
    DOT16(n1B, mb, qcc1); DOT16(cvB, mb, v1); DOT16(cwB, mb, v2);
    const float p1A = tanh_pade(n1A*ra.x*s1);
    const float n2A = 0.5f*(n1A + cvA - mv1*ra.y);
    const float p2A = tanh_pade(n2A*ra.x*s2);
    const float p3A = tanh_pade(0.5f*(n2A + cwA - mv2*ra.y)*ra.x*s3);
    const float p1B = tanh_pade(n1B*rb.x*s1);
    const float n2B = 0.5f*(n1B + cvB - mv1*rb.y);
    const float p2B = tanh_pade(n2B*rb.x*s2);
    const float p3B = tanh_pade(0.5f*(n2B + cwB - mv2*rb.y)*rb.x*s3);
    const float eA = __expf(p1A*cvA + p2A*cwA);
    const float eB = __expf(p1B*cvB + p2B*cwB);
    const float SA = wave_sum64_all(eA);
    const float SB = wave_sum64_all(eB);
    const float wA = eA*__frcp_rn(SA) + p3A;
    const float wB = eB*__frcp_rn(SB) + p3B;
    #pragma unroll
    for (int d=0;d<16;d++){ acc[d] += wA*ma[d]; acc[d] += wB*mb[d]; }
  }
  ST16(part + (((size_t)(q<<cshift) + ch)*64 + c)*16, acc);
}

// ---------------- R3: reduce -> squash -> out ----------------
__global__ __launch_bounds__(64) void reduce3_kernel(const float* __restrict__ part,
                                                     float* __restrict__ out,
                                                     int nchunk)
{
  const int q = blockIdx.x, c = threadIdx.x;
  float hv[16];
  #pragma unroll
  for (int d=0;d<16;d++) hv[d]=0.f;
  const float* pp = part + ((size_t)q*nchunk*64 + c)*16;
  for (int ch=0; ch<nchunk; ch++, pp += 1024){
    float t[16]; LD16(t, pp);
    #pragma unroll
    for (int d=0;d<16;d++) hv[d]+=t[d];
  }
  float n2=0.f;
  #pragma unroll
  for (int d=0;d<16;d++) n2 += hv[d]*hv[d];
  const float sc = n2 / ((1.0f+n2)*sqrtf(n2+1e-8f));
  float o[16];
  #pragma unroll
  for (int d=0;d<16;d++) o[d] = hv[d]*sc;
  ST16(out + (size_t)q*CD + c*16, o);
}

extern "C" void kernel_launch(void* const* d_in, const int* in_sizes, int n_in,
                              void* d_out, int out_size, void* d_ws, size_t ws_size,
                              hipStream_t stream)
{
  const float* m  = (const float*)d_in[0];
  const float* q  = (const float*)d_in[1];
  const float* Ww = (const float*)d_in[2];
  const float* Wb = (const float*)d_in[3];
  float* out = (float*)d_out;

  char* ws = (char*)d_ws;
  float*  hat  = (float*) (ws + 0);          // 4,194,304 B
  float2* rs   = (float2*)(ws + 4194304);    //   262,144 B
  float*  v1g  = (float*) (ws + 4456448);    // 2,097,152 B
  float*  v2g  = (float*) (ws + 6553600);    // 2,097,152 B
  float2* aux1 = (float2*)(ws + 8650752);    //   262,144 B
  float2* aux2 = (float2*)(ws + 8912896);    //   262,144 B
  float*  part = (float*) (ws + 9175040);    // nchunk * 2,097,152 B

  // pick largest nchunk whose partial buffer fits the workspace
  int nchunk = 16, cshift = 4;
  while (nchunk > 1 && 9175040ull + (size_t)nchunk*2097152ull > ws_size){ nchunk >>= 1; cshift--; }
  const int ilen = 512 / nchunk;
  const int pblocks = (QN/4)*nchunk;   // blocks: (q-group of 4) x i-chunk; 4 waves/block

  dim3 g0(16,16);
  gemm_hat<<<g0, 256, 0, stream>>>(m, q, Ww, Wb, hat);
  stats_kernel<<<128, 256, 0, stream>>>(hat, rs);
  pass1_kernel<<<pblocks, 256, 0, stream>>>(hat, rs, part, ilen, nchunk, cshift);
  reduce1_kernel<<<512, 64, 0, stream>>>(hat, part, v1g, aux1, nchunk);
  pass2_kernel<<<pblocks, 256, 0, stream>>>(hat, rs, v1g, aux1, part, ilen, nchunk, cshift);
  reduce2_kernel<<<512, 64, 0, stream>>>(hat, part, v1g, v2g, aux2, nchunk);
  pass3_kernel<<<pblocks, 256, 0, stream>>>(hat, rs, v1g, v2g, aux1, aux2, part, ilen, nchunk, cshift);
  reduce3_kernel<<<512, 64, 0, stream>>>(part, out, nchunk);
}

// Round 9
// 261.551 us; speedup vs baseline: 1.2159x; 1.2147x over previous
//
#include <hip/hip_runtime.h>
#include <math.h>

#define IN_CAPS 512
#define QN      512
#define IN_DIM  768
#define NCAPS   64
#define DCAPS   16
#define CD      1024   // NCAPS*DCAPS

typedef _Float16 half2_t __attribute__((ext_vector_type(2)));

#if __has_builtin(__builtin_amdgcn_fdot2)
  #define FDOT2(a,b,c) __builtin_amdgcn_fdot2(a,b,c,false)
#else
  #define FDOT2(a,b,c) ((c) + (float)((a).x)*(float)((b).x) + (float)((a).y)*(float)((b).y))
#endif

// tanh via continued-fraction Pade (|x|<=~1.05, err ~4e-6)
__device__ __forceinline__ float tanh_pade(float x){
  const float x2 = x*x;
  const float num = fmaf(x2, x2 + 105.0f, 945.0f);
  const float den = fmaf(x2, fmaf(x2, 15.0f, 420.0f), 945.0f);
  return x * num * __frcp_rn(den);
}

template<int CTRL>
__device__ __forceinline__ float dpp_add(float v){
  int r = __builtin_amdgcn_update_dpp(0, __float_as_int(v), CTRL, 0xF, 0xF, true);
  return v + __int_as_float(r);
}

// full 64-lane sum -> uniform scalar (pure DPP + readlane)
__device__ __forceinline__ float wave_sum64_all(float v){
  v = dpp_add<0xB1>(v);
  v = dpp_add<0x4E>(v);
  v = dpp_add<0x141>(v);
  v = dpp_add<0x140>(v);
  v = dpp_add<0x142>(v);
  v = dpp_add<0x143>(v);
  return __int_as_float(__builtin_amdgcn_readlane(__float_as_int(v), 63));
}

#define LD16(dst, ptr) { const float4* _p=(const float4*)(ptr); \
  float4 _a=_p[0], _b=_p[1], _c=_p[2], _d=_p[3]; \
  dst[0]=_a.x; dst[1]=_a.y; dst[2]=_a.z; dst[3]=_a.w; \
  dst[4]=_b.x; dst[5]=_b.y; dst[6]=_b.z; dst[7]=_b.w; \
  dst[8]=_c.x; dst[9]=_c.y; dst[10]=_c.z; dst[11]=_c.w; \
  dst[12]=_d.x; dst[13]=_d.y; dst[14]=_d.z; dst[15]=_d.w; }

#define ST16(ptr, src) { float4* _p=(float4*)(ptr); \
  _p[0]=make_float4(src[0],src[1],src[2],src[3]); \
  _p[1]=make_float4(src[4],src[5],src[6],src[7]); \
  _p[2]=make_float4(src[8],src[9],src[10],src[11]); \
  _p[3]=make_float4(src[12],src[13],src[14],src[15]); }

// load 8 packed half2 (32B) from 2 consecutive float4s
#define LDH(dst, ptrf4) { const float4* _p=(const float4*)(ptrf4); \
  float4 _a=_p[0], _b=_p[1]; \
  dst[0]=__builtin_bit_cast(half2_t,_a.x); dst[1]=__builtin_bit_cast(half2_t,_a.y); \
  dst[2]=__builtin_bit_cast(half2_t,_a.z); dst[3]=__builtin_bit_cast(half2_t,_a.w); \
  dst[4]=__builtin_bit_cast(half2_t,_b.x); dst[5]=__builtin_bit_cast(half2_t,_b.y); \
  dst[6]=__builtin_bit_cast(half2_t,_b.z); dst[7]=__builtin_bit_cast(half2_t,_b.w); }

// pack float[16] -> 2 float4 of half2
#define PACK8(f4a, f4b, src) { float _t[8]; \
  _Pragma("unroll") for (int _j=0;_j<8;_j++){ half2_t _h; _h.x=(_Float16)src[2*_j]; _h.y=(_Float16)src[2*_j+1]; _t[_j]=__builtin_bit_cast(float,_h);} \
  f4a = make_float4(_t[0],_t[1],_t[2],_t[3]); f4b = make_float4(_t[4],_t[5],_t[6],_t[7]); }

// dot of 16 f16 elems held as 8 half2, f32 accumulate, 2-way split chains
#define DOTH(res, m, v) { float _r0=0.f,_r1=0.f; \
  _Pragma("unroll") for (int _j=0;_j<8;_j+=2){ _r0=FDOT2(m[_j],v[_j],_r0); _r1=FDOT2(m[_j+1],v[_j+1],_r1);} \
  res=_r0+_r1; }

// acc[16] f32 += w * m(h16)
#define ACCUM(acc, m, w) { \
  _Pragma("unroll") for (int _j=0;_j<8;_j++){ \
    acc[2*_j]   = fmaf(w, (float)m[_j].x, acc[2*_j]); \
    acc[2*_j+1] = fmaf(w, (float)m[_j].y, acc[2*_j+1]); } }

// ---------------- K0: hat = [m;q] @ W_w + W_b (+ f16 copy of m-rows) ----------------
__global__ __launch_bounds__(256) void gemm_hat(const float* __restrict__ m,
                                                const float* __restrict__ q,
                                                const float* __restrict__ Ww,
                                                const float* __restrict__ Wb,
                                                float* __restrict__ hat,
                                                _Float16* __restrict__ hatH)
{
  __shared__ float As[16][65];
  __shared__ float Bs[16][65];
  const int tid = threadIdx.x;
  const int bm = blockIdx.y, bn = blockIdx.x;
  const int tx = tid & 15, ty = tid >> 4;

  float acc[4][4];
  #pragma unroll
  for (int a=0;a<4;a++)
    #pragma unroll
    for (int b=0;b<4;b++) acc[a][b]=0.0f;

  const int r  = tid >> 2;
  const int kk = (tid & 3) << 2;
  const int row = bm*64 + r;
  const float* srcA = (row < IN_CAPS) ? (m + row*IN_DIM) : (q + (row-IN_CAPS)*IN_DIM);
  const int krow = tid >> 4;
  const int cc   = (tid & 15) << 2;

  for (int k0=0; k0<IN_DIM; k0+=16){
    float4 av = *(const float4*)(srcA + k0 + kk);
    As[kk+0][r]=av.x; As[kk+1][r]=av.y; As[kk+2][r]=av.z; As[kk+3][r]=av.w;
    float4 bv = *(const float4*)(Ww + (size_t)(k0+krow)*CD + bn*64 + cc);
    Bs[krow][cc+0]=bv.x; Bs[krow][cc+1]=bv.y; Bs[krow][cc+2]=bv.z; Bs[krow][cc+3]=bv.w;
    __syncthreads();
    #pragma unroll
    for (int k=0;k<16;k++){
      float a[4], b[4];
      #pragma unroll
      for (int j=0;j<4;j++) a[j] = As[k][ty*4+j];
      #pragma unroll
      for (int j=0;j<4;j++) b[j] = Bs[k][tx*4+j];
      #pragma unroll
      for (int ii=0;ii<4;ii++)
        #pragma unroll
        for (int jj=0;jj<4;jj++) acc[ii][jj] += a[ii]*b[jj];
    }
    __syncthreads();
  }
  const int col0 = bn*64 + tx*4;
  #pragma unroll
  for (int ii=0;ii<4;ii++){
    const int orow = bm*64 + ty*4 + ii;
    float v[4];
    #pragma unroll
    for (int jj=0;jj<4;jj++) v[jj] = acc[ii][jj] + Wb[col0+jj];
    #pragma unroll
    for (int jj=0;jj<4;jj++) hat[(size_t)orow*CD + col0 + jj] = v[jj];
    if (orow < IN_CAPS){
      half2_t h0, h1;
      h0.x=(_Float16)v[0]; h0.y=(_Float16)v[1];
      h1.x=(_Float16)v[2]; h1.y=(_Float16)v[3];
      float2 pk = make_float2(__builtin_bit_cast(float,h0), __builtin_bit_cast(float,h1));
      *(float2*)(hatH + (size_t)orow*CD + col0) = pk;
    }
  }
}

// ---------------- K1: stats for m-rows (rs) + packed centered q (qh, s1) ----------------
__global__ __launch_bounds__(256) void stats_kernel(const float* __restrict__ hat,
                                                    float2* __restrict__ rs,
                                                    float4* __restrict__ qhg,
                                                    float* __restrict__ s1g)
{
  const int t = blockIdx.x*256 + threadIdx.x;   // 0..65535
  const int row = t >> 6, c = t & 63;
  float v[16];
  LD16(v, hat + (size_t)row*CD + c*16);
  float s=0.f;
  #pragma unroll
  for (int d=0;d<16;d++) s += v[d];
  const float mean = s*(1.0f/16.0f);
  float n2=0.f;
  #pragma unroll
  for (int d=0;d<16;d++){ float x=v[d]-mean; n2+=x*x; }
  if (row < IN_CAPS){
    rs[t] = make_float2(__frsqrt_rn(n2 + 1e-12f), s);
  } else {
    const int qi = (row - IN_CAPS)*64 + c;
    float qcc[16];
    #pragma unroll
    for (int d=0;d<16;d++) qcc[d] = v[d]-mean;
    float4 a, b;
    PACK8(a, b, qcc);
    qhg[(size_t)qi*2] = a; qhg[(size_t)qi*2+1] = b;
    s1g[qi] = __frsqrt_rn(n2 + 1e-12f);
  }
}

// decode: wave -> (q, chunk); lane = capsule
#define WDECODE() \
  const int tid = threadIdx.x; \
  const int gw  = blockIdx.x*4 + (tid >> 6); \
  const int q   = gw >> cshift; \
  const int ch  = gw & (nch-1); \
  const int c   = tid & 63;

// ---------------- P1 ----------------
__global__ __launch_bounds__(256, 8) void pass1_kernel(const float4* __restrict__ hatH4,
                                                       const float2* __restrict__ rs_g,
                                                       const float4* __restrict__ qhg,
                                                       const float* __restrict__ s1g,
                                                       float* __restrict__ part,
                                                       int ilen, int nch, int cshift)
{
  WDECODE();
  half2_t qh[8];
  LDH(qh, qhg + (size_t)(q*64+c)*2);
  const float s1 = s1g[q*64+c];

  float acc[16];
  #pragma unroll
  for (int d=0;d<16;d++) acc[d]=0.f;

  const int i0 = ch*ilen;
  const float4* mp = hatH4 + (size_t)i0*128 + c*2;
  const float2* rp = rs_g + i0*64 + c;
  for (int i=0;i<ilen;i++, mp+=128, rp+=64){
    half2_t mh[8];
    LDH(mh, mp);
    const float ra = rp->x;
    float n1;
    DOTH(n1, mh, qh);
    const float w = 0.015625f + tanh_pade(n1*ra*s1);
    ACCUM(acc, mh, w);
  }
  ST16(part + (((size_t)(q<<cshift) + ch)*64 + c)*16, acc);
}

// ---------------- R1: reduce -> v1 (f16 pack) + aux1=(s2, mv1) ----------------
__global__ __launch_bounds__(256) void reduce1_kernel(const float* __restrict__ hat,
                                                      const float* __restrict__ part,
                                                      float4* __restrict__ v1hg,
                                                      float2* __restrict__ aux1,
                                                      int nchunk)
{
  const int tid = threadIdx.x;
  const int q = blockIdx.x*4 + (tid>>6), c = tid & 63;
  float hv[16];
  #pragma unroll
  for (int d=0;d<16;d++) hv[d]=0.f;
  const float* pp = part + ((size_t)q*nchunk*64 + c)*16;
  for (int ch=0; ch<nchunk; ch++, pp += 1024){
    float t[16]; LD16(t, pp);
    #pragma unroll
    for (int d=0;d<16;d++) hv[d]+=t[d];
  }
  float n2=0.f;
  #pragma unroll
  for (int d=0;d<16;d++) n2 += hv[d]*hv[d];
  const float sc = n2 / ((1.0f+n2)*sqrtf(n2+1e-8f));
  float v1[16]; float sv=0.f;
  #pragma unroll
  for (int d=0;d<16;d++){ v1[d]=hv[d]*sc; sv+=v1[d]; }
  float4 a, b;
  PACK8(a, b, v1);
  v1hg[(size_t)(q*64+c)*2] = a; v1hg[(size_t)(q*64+c)*2+1] = b;
  float qc[16]; LD16(qc, hat + (size_t)(IN_CAPS+q)*CD + c*16);
  float s=0.f, ss=0.f;
  #pragma unroll
  for (int d=0;d<16;d++){ const float t2 = 0.5f*(qc[d]+v1[d]); s+=t2; ss+=t2*t2; }
  const float mean = s*(1.0f/16.0f);
  aux1[q*64+c] = make_float2(__frsqrt_rn(ss - 16.0f*mean*mean + 1e-12f), sv*(1.0f/16.0f));
}

// ---------------- P2 ----------------
__global__ __launch_bounds__(256, 8) void pass2_kernel(const float4* __restrict__ hatH4,
                                                       const float2* __restrict__ rs_g,
                                                       const float4* __restrict__ qhg,
                                                       const float* __restrict__ s1g,
                                                       const float4* __restrict__ v1hg,
                                                       const float2* __restrict__ aux1,
                                                       float* __restrict__ part,
                                                       int ilen, int nch, int cshift)
{
  WDECODE();
  half2_t qh[8], v1h[8];
  LDH(qh, qhg + (size_t)(q*64+c)*2);
  LDH(v1h, v1hg + (size_t)(q*64+c)*2);
  const float s1 = s1g[q*64+c];
  const float2 a1 = aux1[q*64+c];
  const float s2 = a1.x, mv1 = a1.y;

  float acc[16];
  #pragma unroll
  for (int d=0;d<16;d++) acc[d]=0.f;

  const int i0 = ch*ilen;
  const float4* mp = hatH4 + (size_t)i0*128 + c*2;
  const float2* rp = rs_g + i0*64 + c;
  for (int i=0;i<ilen;i++, mp+=128, rp+=64){
    half2_t mh[8];
    LDH(mh, mp);
    const float2 ra = *rp;
    float n1, cv1;
    DOTH(n1, mh, qh);
    DOTH(cv1, mh, v1h);
    const float p1 = tanh_pade(n1*ra.x*s1);
    const float p2 = tanh_pade(0.5f*(n1 + cv1 - mv1*ra.y)*ra.x*s2);
    const float e  = __expf(p1*cv1);
    const float S  = wave_sum64_all(e);
    const float w  = e*__frcp_rn(S) + p2;
    ACCUM(acc, mh, w);
  }
  ST16(part + (((size_t)(q<<cshift) + ch)*64 + c)*16, acc);
}

// ---------------- R2: reduce -> v2 (f16 pack) + aux2=(s3, mv2) ----------------
__global__ __launch_bounds__(256) void reduce2_kernel(const float* __restrict__ hat,
                                                      const float* __restrict__ part,
                                                      const float4* __restrict__ v1hg,
                                                      float4* __restrict__ v2hg,
                                                      float2* __restrict__ aux2,
                                                      int nchunk)
{
  const int tid = threadIdx.x;
  const int q = blockIdx.x*4 + (tid>>6), c = tid & 63;
  float hv[16];
  #pragma unroll
  for (int d=0;d<16;d++) hv[d]=0.f;
  const float* pp = part + ((size_t)q*nchunk*64 + c)*16;
  for (int ch=0; ch<nchunk; ch++, pp += 1024){
    float t[16]; LD16(t, pp);
    #pragma unroll
    for (int d=0;d<16;d++) hv[d]+=t[d];
  }
  float n2=0.f;
  #pragma unroll
  for (int d=0;d<16;d++) n2 += hv[d]*hv[d];
  const float sc = n2 / ((1.0f+n2)*sqrtf(n2+1e-8f));
  float v2[16]; float sv=0.f;
  #pragma unroll
  for (int d=0;d<16;d++){ v2[d]=hv[d]*sc; sv+=v2[d]; }
  float4 a, b;
  PACK8(a, b, v2);
  v2hg[(size_t)(q*64+c)*2] = a; v2hg[(size_t)(q*64+c)*2+1] = b;

  half2_t v1h[8];
  LDH(v1h, v1hg + (size_t)(q*64+c)*2);
  float qc[16];  LD16(qc, hat + (size_t)(IN_CAPS+q)*CD + c*16);
  float s=0.f, ss=0.f;
  #pragma unroll
  for (int j=0;j<8;j++){
    const float t3a = 0.25f*qc[2*j]   + 0.25f*(float)v1h[j].x + 0.5f*v2[2*j];
    const float t3b = 0.25f*qc[2*j+1] + 0.25f*(float)v1h[j].y + 0.5f*v2[2*j+1];
    s += t3a + t3b; ss += t3a*t3a + t3b*t3b;
  }
  const float mean = s*(1.0f/16.0f);
  aux2[q*64+c] = make_float2(__frsqrt_rn(ss - 16.0f*mean*mean + 1e-12f), sv*(1.0f/16.0f));
}

// ---------------- P3 ----------------
__global__ __launch_bounds__(256, 6) void pass3_kernel(const float4* __restrict__ hatH4,
                                                       const float2* __restrict__ rs_g,
                                                       const float4* __restrict__ qhg,
                                                       const float* __restrict__ s1g,
                                                       const float4* __restrict__ v1hg,
                                                       const float4* __restrict__ v2hg,
                                                       const float2* __restrict__ aux1,
                                                       const float2* __restrict__ aux2,
                                                       float* __restrict__ part,
                                                       int ilen, int nch, int cshift)
{
  WDECODE();
  half2_t qh[8], v1h[8], v2h[8];
  LDH(qh, qhg + (size_t)(q*64+c)*2);
  LDH(v1h, v1hg + (size_t)(q*64+c)*2);
  LDH(v2h, v2hg + (size_t)(q*64+c)*2);
  const float s1 = s1g[q*64+c];
  const float2 a1 = aux1[q*64+c];
  const float2 a2 = aux2[q*64+c];
  const float s2 = a1.x, mv1 = a1.y, s3 = a2.x, mv2 = a2.y;

  float acc[16];
  #pragma unroll
  for (int d=0;d<16;d++) acc[d]=0.f;

  const int i0 = ch*ilen;
  const float4* mp = hatH4 + (size_t)i0*128 + c*2;
  const float2* rp = rs_g + i0*64 + c;
  for (int i=0;i<ilen;i++, mp+=128, rp+=64){
    half2_t mh[8];
    LDH(mh, mp);
    const float2 ra = *rp;
    float n1, cv1, cv2;
    DOTH(n1, mh, qh);
    DOTH(cv1, mh, v1h);
    DOTH(cv2, mh, v2h);
    const float p1 = tanh_pade(n1*ra.x*s1);
    const float n2d = 0.5f*(n1 + cv1 - mv1*ra.y);
    const float p2 = tanh_pade(n2d*ra.x*s2);
    const float p3 = tanh_pade(0.5f*(n2d + cv2 - mv2*ra.y)*ra.x*s3);
    const float e  = __expf(fmaf(p1, cv1, p2*cv2));
    const float S  = wave_sum64_all(e);
    const float w  = e*__frcp_rn(S) + p3;
    ACCUM(acc, mh, w);
  }
  ST16(part + (((size_t)(q<<cshift) + ch)*64 + c)*16, acc);
}

// ---------------- R3: reduce -> squash -> out ----------------
__global__ __launch_bounds__(256) void reduce3_kernel(const float* __restrict__ part,
                                                      float* __restrict__ out,
                                                      int nchunk)
{
  const int tid = threadIdx.x;
  const int q = blockIdx.x*4 + (tid>>6), c = tid & 63;
  float hv[16];
  #pragma unroll
  for (int d=0;d<16;d++) hv[d]=0.f;
  const float* pp = part + ((size_t)q*nchunk*64 + c)*16;
  for (int ch=0; ch<nchunk; ch++, pp += 1024){
    float t[16]; LD16(t, pp);
    #pragma unroll
    for (int d=0;d<16;d++) hv[d]+=t[d];
  }
  float n2=0.f;
  #pragma unroll
  for (int d=0;d<16;d++) n2 += hv[d]*hv[d];
  const float sc = n2 / ((1.0f+n2)*sqrtf(n2+1e-8f));
  float o[16];
  #pragma unroll
  for (int d=0;d<16;d++) o[d] = hv[d]*sc;
  ST16(out + (size_t)q*CD + c*16, o);
}

extern "C" void kernel_launch(void* const* d_in, const int* in_sizes, int n_in,
                              void* d_out, int out_size, void* d_ws, size_t ws_size,
                              hipStream_t stream)
{
  const float* m  = (const float*)d_in[0];
  const float* q  = (const float*)d_in[1];
  const float* Ww = (const float*)d_in[2];
  const float* Wb = (const float*)d_in[3];
  float* out = (float*)d_out;

  // Workspace layout (sizes in bytes):
  //   hat  : 1024*1024*4          = 4,194,304
  //   rs   : 512*64*8             =   262,144
  //   hatH : 512*1024*2           = 1,048,576
  //   qhg  : 512*64*32 (8 half2)  = 1,048,576   <-- was 512 KB (R8 bug: overflow into s1g)
  //   s1g  : 512*64*4             =   131,072
  //   v1hg : 1,048,576            <-- was 512 KB
  //   v2hg : 1,048,576            <-- was 512 KB
  //   aux1 : 262,144
  //   aux2 : 262,144
  //   part : nchunk * 2,097,152
  char* ws = (char*)d_ws;
  float*    hat  = (float*)   (ws + 0);
  float2*   rs   = (float2*)  (ws + 4194304);
  _Float16* hatH = (_Float16*)(ws + 4456448);
  float4*   qhg  = (float4*)  (ws + 5505024);
  float*    s1g  = (float*)   (ws + 6553600);
  float4*   v1hg = (float4*)  (ws + 6684672);
  float4*   v2hg = (float4*)  (ws + 7733248);
  float2*   aux1 = (float2*)  (ws + 8781824);
  float2*   aux2 = (float2*)  (ws + 9043968);
  float*    part = (float*)   (ws + 9306112);

  int nchunk = 16, cshift = 4;
  while (nchunk > 1 && 9306112ull + (size_t)nchunk*2097152ull > ws_size){ nchunk >>= 1; cshift--; }
  const int ilen = 512 / nchunk;
  const int pblocks = (QN*nchunk)/4;   // 4 waves/block, wave = (q, chunk)

  dim3 g0(16,16);
  gemm_hat<<<g0, 256, 0, stream>>>(m, q, Ww, Wb, hat, hatH);
  stats_kernel<<<256, 256, 0, stream>>>(hat, rs, qhg, s1g);
  pass1_kernel<<<pblocks, 256, 0, stream>>>((const float4*)hatH, rs, qhg, s1g, part, ilen, nchunk, cshift);
  reduce1_kernel<<<128, 256, 0, stream>>>(hat, part, v1hg, aux1, nchunk);
  pass2_kernel<<<pblocks, 256, 0, stream>>>((const float4*)hatH, rs, qhg, s1g, v1hg, aux1, part, ilen, nchunk, cshift);
  reduce2_kernel<<<128, 256, 0, stream>>>(hat, part, v1hg, v2hg, aux2, nchunk);
  pass3_kernel<<<pblocks, 256, 0, stream>>>((const float4*)hatH, rs, qhg, s1g, v1hg, v2hg, aux1, aux2, part, ilen, nchunk, cshift);
  reduce3_kernel<<<128, 256, 0, stream>>>(part, out, nchunk);
}

// Round 10
// 257.349 us; speedup vs baseline: 1.2358x; 1.0163x over previous
//
#include <hip/hip_runtime.h>
#include <math.h>

#define IN_CAPS 512
#define QN      512
#define IN_DIM  768
#define NCAPS   64
#define DCAPS   16
#define CD      1024   // NCAPS*DCAPS

typedef _Float16 half2_t __attribute__((ext_vector_type(2)));

#if __has_builtin(__builtin_amdgcn_fdot2)
  #define FDOT2(a,b,c) __builtin_amdgcn_fdot2(a,b,c,false)
#else
  #define FDOT2(a,b,c) ((c) + (float)((a).x)*(float)((b).x) + (float)((a).y)*(float)((b).y))
#endif

// tanh via continued-fraction Pade (|x|<=~1.05, err ~4e-6)
__device__ __forceinline__ float tanh_pade(float x){
  const float x2 = x*x;
  const float num = fmaf(x2, x2 + 105.0f, 945.0f);
  const float den = fmaf(x2, fmaf(x2, 15.0f, 420.0f), 945.0f);
  return x * num * __frcp_rn(den);
}

template<int CTRL>
__device__ __forceinline__ float dpp_add(float v){
  int r = __builtin_amdgcn_update_dpp(0, __float_as_int(v), CTRL, 0xF, 0xF, true);
  return v + __int_as_float(r);
}

// full 64-lane sum -> uniform scalar (pure DPP + readlane)
__device__ __forceinline__ float wave_sum64_all(float v){
  v = dpp_add<0xB1>(v);
  v = dpp_add<0x4E>(v);
  v = dpp_add<0x141>(v);
  v = dpp_add<0x140>(v);
  v = dpp_add<0x142>(v);
  v = dpp_add<0x143>(v);
  return __int_as_float(__builtin_amdgcn_readlane(__float_as_int(v), 63));
}

#define LD16(dst, ptr) { const float4* _p=(const float4*)(ptr); \
  float4 _a=_p[0], _b=_p[1], _c=_p[2], _d=_p[3]; \
  dst[0]=_a.x; dst[1]=_a.y; dst[2]=_a.z; dst[3]=_a.w; \
  dst[4]=_b.x; dst[5]=_b.y; dst[6]=_b.z; dst[7]=_b.w; \
  dst[8]=_c.x; dst[9]=_c.y; dst[10]=_c.z; dst[11]=_c.w; \
  dst[12]=_d.x; dst[13]=_d.y; dst[14]=_d.z; dst[15]=_d.w; }

#define ST16(ptr, src) { float4* _p=(float4*)(ptr); \
  _p[0]=make_float4(src[0],src[1],src[2],src[3]); \
  _p[1]=make_float4(src[4],src[5],src[6],src[7]); \
  _p[2]=make_float4(src[8],src[9],src[10],src[11]); \
  _p[3]=make_float4(src[12],src[13],src[14],src[15]); }

// load 8 packed half2 (32B) from 2 consecutive float4s
#define LDH(dst, ptrf4) { const float4* _p=(const float4*)(ptrf4); \
  float4 _a=_p[0], _b=_p[1]; \
  dst[0]=__builtin_bit_cast(half2_t,_a.x); dst[1]=__builtin_bit_cast(half2_t,_a.y); \
  dst[2]=__builtin_bit_cast(half2_t,_a.z); dst[3]=__builtin_bit_cast(half2_t,_a.w); \
  dst[4]=__builtin_bit_cast(half2_t,_b.x); dst[5]=__builtin_bit_cast(half2_t,_b.y); \
  dst[6]=__builtin_bit_cast(half2_t,_b.z); dst[7]=__builtin_bit_cast(half2_t,_b.w); }

// pack float[16] -> 2 float4 of half2
#define PACK8(f4a, f4b, src) { float _t[8]; \
  _Pragma("unroll") for (int _j=0;_j<8;_j++){ half2_t _h; _h.x=(_Float16)src[2*_j]; _h.y=(_Float16)src[2*_j+1]; _t[_j]=__builtin_bit_cast(float,_h);} \
  f4a = make_float4(_t[0],_t[1],_t[2],_t[3]); f4b = make_float4(_t[4],_t[5],_t[6],_t[7]); }

// dot of 16 f16 elems held as 8 half2, f32 accumulate, 2-way split chains
#define DOTH(res, m, v) { float _r0=0.f,_r1=0.f; \
  _Pragma("unroll") for (int _j=0;_j<8;_j+=2){ _r0=FDOT2(m[_j],v[_j],_r0); _r1=FDOT2(m[_j+1],v[_j+1],_r1);} \
  res=_r0+_r1; }

// acc[16] f32 += w * m(h16)   (compiler should emit v_fma_mix)
#define ACCUM(acc, m, w) { \
  _Pragma("unroll") for (int _j=0;_j<8;_j++){ \
    acc[2*_j]   = fmaf(w, (float)m[_j].x, acc[2*_j]); \
    acc[2*_j+1] = fmaf(w, (float)m[_j].y, acc[2*_j+1]); } }

// ---------------- K0: hat = [m;q] @ W_w + W_b (+ f16 copy of m-rows) ----------------
__global__ __launch_bounds__(256) void gemm_hat(const float* __restrict__ m,
                                                const float* __restrict__ q,
                                                const float* __restrict__ Ww,
                                                const float* __restrict__ Wb,
                                                float* __restrict__ hat,
                                                _Float16* __restrict__ hatH)
{
  __shared__ float As[16][65];
  __shared__ float Bs[16][65];
  const int tid = threadIdx.x;
  const int bm = blockIdx.y, bn = blockIdx.x;
  const int tx = tid & 15, ty = tid >> 4;

  float acc[4][4];
  #pragma unroll
  for (int a=0;a<4;a++)
    #pragma unroll
    for (int b=0;b<4;b++) acc[a][b]=0.0f;

  const int r  = tid >> 2;
  const int kk = (tid & 3) << 2;
  const int row = bm*64 + r;
  const float* srcA = (row < IN_CAPS) ? (m + row*IN_DIM) : (q + (row-IN_CAPS)*IN_DIM);
  const int krow = tid >> 4;
  const int cc   = (tid & 15) << 2;

  for (int k0=0; k0<IN_DIM; k0+=16){
    float4 av = *(const float4*)(srcA + k0 + kk);
    As[kk+0][r]=av.x; As[kk+1][r]=av.y; As[kk+2][r]=av.z; As[kk+3][r]=av.w;
    float4 bv = *(const float4*)(Ww + (size_t)(k0+krow)*CD + bn*64 + cc);
    Bs[krow][cc+0]=bv.x; Bs[krow][cc+1]=bv.y; Bs[krow][cc+2]=bv.z; Bs[krow][cc+3]=bv.w;
    __syncthreads();
    #pragma unroll
    for (int k=0;k<16;k++){
      float a[4], b[4];
      #pragma unroll
      for (int j=0;j<4;j++) a[j] = As[k][ty*4+j];
      #pragma unroll
      for (int j=0;j<4;j++) b[j] = Bs[k][tx*4+j];
      #pragma unroll
      for (int ii=0;ii<4;ii++)
        #pragma unroll
        for (int jj=0;jj<4;jj++) acc[ii][jj] += a[ii]*b[jj];
    }
    __syncthreads();
  }
  const int col0 = bn*64 + tx*4;
  #pragma unroll
  for (int ii=0;ii<4;ii++){
    const int orow = bm*64 + ty*4 + ii;
    float v[4];
    #pragma unroll
    for (int jj=0;jj<4;jj++) v[jj] = acc[ii][jj] + Wb[col0+jj];
    #pragma unroll
    for (int jj=0;jj<4;jj++) hat[(size_t)orow*CD + col0 + jj] = v[jj];
    if (orow < IN_CAPS){
      half2_t h0, h1;
      h0.x=(_Float16)v[0]; h0.y=(_Float16)v[1];
      h1.x=(_Float16)v[2]; h1.y=(_Float16)v[3];
      float2 pk = make_float2(__builtin_bit_cast(float,h0), __builtin_bit_cast(float,h1));
      *(float2*)(hatH + (size_t)orow*CD + col0) = pk;
    }
  }
}

// ---------------- K1: stats for m-rows (rs) + packed centered q (qh, s1) ----------------
__global__ __launch_bounds__(256) void stats_kernel(const float* __restrict__ hat,
                                                    float2* __restrict__ rs,
                                                    float4* __restrict__ qhg,
                                                    float* __restrict__ s1g)
{
  const int t = blockIdx.x*256 + threadIdx.x;   // 0..65535
  const int row = t >> 6, c = t & 63;
  float v[16];
  LD16(v, hat + (size_t)row*CD + c*16);
  float s=0.f;
  #pragma unroll
  for (int d=0;d<16;d++) s += v[d];
  const float mean = s*(1.0f/16.0f);
  float n2=0.f;
  #pragma unroll
  for (int d=0;d<16;d++){ float x=v[d]-mean; n2+=x*x; }
  if (row < IN_CAPS){
    rs[t] = make_float2(__frsqrt_rn(n2 + 1e-12f), s);
  } else {
    const int qi = (row - IN_CAPS)*64 + c;
    float qcc[16];
    #pragma unroll
    for (int d=0;d<16;d++) qcc[d] = v[d]-mean;
    float4 a, b;
    PACK8(a, b, qcc);
    qhg[(size_t)qi*2] = a; qhg[(size_t)qi*2+1] = b;
    s1g[qi] = __frsqrt_rn(n2 + 1e-12f);
  }
}

// decode: wave -> (q, chunk); lane = capsule
#define WDECODE() \
  const int tid = threadIdx.x; \
  const int gw  = blockIdx.x*4 + (tid >> 6); \
  const int q   = gw >> cshift; \
  const int ch  = gw & (nch-1); \
  const int c   = tid & 63;

// ---------------- P1 ----------------
__global__ __launch_bounds__(256) void pass1_kernel(const float4* __restrict__ hatH4,
                                                    const float2* __restrict__ rs_g,
                                                    const float4* __restrict__ qhg,
                                                    const float* __restrict__ s1g,
                                                    float* __restrict__ part,
                                                    int ilen, int nch, int cshift)
{
  WDECODE();
  half2_t qh[8];
  LDH(qh, qhg + (size_t)(q*64+c)*2);
  const float s1 = s1g[q*64+c];

  float acc[16];
  #pragma unroll
  for (int d=0;d<16;d++) acc[d]=0.f;

  const int i0 = ch*ilen;
  const float4* mp = hatH4 + (size_t)i0*128 + c*2;
  const float2* rp = rs_g + i0*64 + c;
  for (int i=0;i<ilen;i+=2, mp+=256, rp+=128){
    half2_t ma[8], mb[8];
    LDH(ma, mp); LDH(mb, mp+128);
    const float ra = rp[0].x, rb = rp[64].x;
    float nA, nB;
    DOTH(nA, ma, qh);
    DOTH(nB, mb, qh);
    const float wA = 0.015625f + tanh_pade(nA*ra*s1);
    const float wB = 0.015625f + tanh_pade(nB*rb*s1);
    ACCUM(acc, ma, wA);
    ACCUM(acc, mb, wB);
  }
  ST16(part + (((size_t)(q<<cshift) + ch)*64 + c)*16, acc);
}

// ---------------- R1: reduce -> v1 (f16 pack) + aux1=(s2, mv1) ----------------
__global__ __launch_bounds__(256) void reduce1_kernel(const float* __restrict__ hat,
                                                      const float* __restrict__ part,
                                                      float4* __restrict__ v1hg,
                                                      float2* __restrict__ aux1,
                                                      int nchunk)
{
  const int tid = threadIdx.x;
  const int q = blockIdx.x*4 + (tid>>6), c = tid & 63;
  float hv[16];
  #pragma unroll
  for (int d=0;d<16;d++) hv[d]=0.f;
  const float* pp = part + ((size_t)q*nchunk*64 + c)*16;
  for (int ch=0; ch<nchunk; ch++, pp += 1024){
    float t[16]; LD16(t, pp);
    #pragma unroll
    for (int d=0;d<16;d++) hv[d]+=t[d];
  }
  float n2=0.f;
  #pragma unroll
  for (int d=0;d<16;d++) n2 += hv[d]*hv[d];
  const float sc = n2 / ((1.0f+n2)*sqrtf(n2+1e-8f));
  float v1[16]; float sv=0.f;
  #pragma unroll
  for (int d=0;d<16;d++){ v1[d]=hv[d]*sc; sv+=v1[d]; }
  float4 a, b;
  PACK8(a, b, v1);
  v1hg[(size_t)(q*64+c)*2] = a; v1hg[(size_t)(q*64+c)*2+1] = b;
  float qc[16]; LD16(qc, hat + (size_t)(IN_CAPS+q)*CD + c*16);
  float s=0.f, ss=0.f;
  #pragma unroll
  for (int d=0;d<16;d++){ const float t2 = 0.5f*(qc[d]+v1[d]); s+=t2; ss+=t2*t2; }
  const float mean = s*(1.0f/16.0f);
  aux1[q*64+c] = make_float2(__frsqrt_rn(ss - 16.0f*mean*mean + 1e-12f), sv*(1.0f/16.0f));
}

// ---------------- P2 ----------------
__global__ __launch_bounds__(256) void pass2_kernel(const float4* __restrict__ hatH4,
                                                    const float2* __restrict__ rs_g,
                                                    const float4* __restrict__ qhg,
                                                    const float* __restrict__ s1g,
                                                    const float4* __restrict__ v1hg,
                                                    const float2* __restrict__ aux1,
                                                    float* __restrict__ part,
                                                    int ilen, int nch, int cshift)
{
  WDECODE();
  half2_t qh[8], v1h[8];
  LDH(qh, qhg + (size_t)(q*64+c)*2);
  LDH(v1h, v1hg + (size_t)(q*64+c)*2);
  const float s1 = s1g[q*64+c];
  const float2 a1 = aux1[q*64+c];
  const float s2 = a1.x, mv1 = a1.y;

  float acc[16];
  #pragma unroll
  for (int d=0;d<16;d++) acc[d]=0.f;

  const int i0 = ch*ilen;
  const float4* mp = hatH4 + (size_t)i0*128 + c*2;
  const float2* rp = rs_g + i0*64 + c;
  for (int i=0;i<ilen;i+=2, mp+=256, rp+=128){
    half2_t ma[8], mb[8];
    LDH(ma, mp); LDH(mb, mp+128);
    const float2 ra = rp[0], rb = rp[64];
    float n1A, cvA, n1B, cvB;
    DOTH(n1A, ma, qh);  DOTH(cvA, ma, v1h);
    DOTH(n1B, mb, qh);  DOTH(cvB, mb, v1h);
    const float p1A = tanh_pade(n1A*ra.x*s1);
    const float p2A = tanh_pade(0.5f*(n1A + cvA - mv1*ra.y)*ra.x*s2);
    const float p1B = tanh_pade(n1B*rb.x*s1);
    const float p2B = tanh_pade(0.5f*(n1B + cvB - mv1*rb.y)*rb.x*s2);
    const float eA = __expf(p1A*cvA);
    const float eB = __expf(p1B*cvB);
    const float SA = wave_sum64_all(eA);
    const float SB = wave_sum64_all(eB);
    const float wA = eA*__frcp_rn(SA) + p2A;
    const float wB = eB*__frcp_rn(SB) + p2B;
    ACCUM(acc, ma, wA);
    ACCUM(acc, mb, wB);
  }
  ST16(part + (((size_t)(q<<cshift) + ch)*64 + c)*16, acc);
}

// ---------------- R2: reduce -> v2 (f16 pack) + aux2=(s3, mv2) ----------------
__global__ __launch_bounds__(256) void reduce2_kernel(const float* __restrict__ hat,
                                                      const float* __restrict__ part,
                                                      const float4* __restrict__ v1hg,
                                                      float4* __restrict__ v2hg,
                                                      float2* __restrict__ aux2,
                                                      int nchunk)
{
  const int tid = threadIdx.x;
  const int q = blockIdx.x*4 + (tid>>6), c = tid & 63;
  float hv[16];
  #pragma unroll
  for (int d=0;d<16;d++) hv[d]=0.f;
  const float* pp = part + ((size_t)q*nchunk*64 + c)*16;
  for (int ch=0; ch<nchunk; ch++, pp += 1024){
    float t[16]; LD16(t, pp);
    #pragma unroll
    for (int d=0;d<16;d++) hv[d]+=t[d];
  }
  float n2=0.f;
  #pragma unroll
  for (int d=0;d<16;d++) n2 += hv[d]*hv[d];
  const float sc = n2 / ((1.0f+n2)*sqrtf(n2+1e-8f));
  float v2[16]; float sv=0.f;
  #pragma unroll
  for (int d=0;d<16;d++){ v2[d]=hv[d]*sc; sv+=v2[d]; }
  float4 a, b;
  PACK8(a, b, v2);
  v2hg[(size_t)(q*64+c)*2] = a; v2hg[(size_t)(q*64+c)*2+1] = b;

  half2_t v1h[8];
  LDH(v1h, v1hg + (size_t)(q*64+c)*2);
  float qc[16];  LD16(qc, hat + (size_t)(IN_CAPS+q)*CD + c*16);
  float s=0.f, ss=0.f;
  #pragma unroll
  for (int j=0;j<8;j++){
    const float t3a = 0.25f*qc[2*j]   + 0.25f*(float)v1h[j].x + 0.5f*v2[2*j];
    const float t3b = 0.25f*qc[2*j+1] + 0.25f*(float)v1h[j].y + 0.5f*v2[2*j+1];
    s += t3a + t3b; ss += t3a*t3a + t3b*t3b;
  }
  const float mean = s*(1.0f/16.0f);
  aux2[q*64+c] = make_float2(__frsqrt_rn(ss - 16.0f*mean*mean + 1e-12f), sv*(1.0f/16.0f));
}

// ---------------- P3 ----------------
__global__ __launch_bounds__(256) void pass3_kernel(const float4* __restrict__ hatH4,
                                                    const float2* __restrict__ rs_g,
                                                    const float4* __restrict__ qhg,
                                                    const float* __restrict__ s1g,
                                                    const float4* __restrict__ v1hg,
                                                    const float4* __restrict__ v2hg,
                                                    const float2* __restrict__ aux1,
                                                    const float2* __restrict__ aux2,
                                                    float* __restrict__ part,
                                                    int ilen, int nch, int cshift)
{
  WDECODE();
  half2_t qh[8], v1h[8], v2h[8];
  LDH(qh, qhg + (size_t)(q*64+c)*2);
  LDH(v1h, v1hg + (size_t)(q*64+c)*2);
  LDH(v2h, v2hg + (size_t)(q*64+c)*2);
  const float s1 = s1g[q*64+c];
  const float2 a1 = aux1[q*64+c];
  const float2 a2 = aux2[q*64+c];
  const float s2 = a1.x, mv1 = a1.y, s3 = a2.x, mv2 = a2.y;

  float acc[16];
  #pragma unroll
  for (int d=0;d<16;d++) acc[d]=0.f;

  const int i0 = ch*ilen;
  const float4* mp = hatH4 + (size_t)i0*128 + c*2;
  const float2* rp = rs_g + i0*64 + c;
  for (int i=0;i<ilen;i+=2, mp+=256, rp+=128){
    half2_t ma[8], mb[8];
    LDH(ma, mp); LDH(mb, mp+128);
    const float2 ra = rp[0], rb = rp[64];
    float n1A, cvA, cwA, n1B, cvB, cwB;
    DOTH(n1A, ma, qh);  DOTH(cvA, ma, v1h);  DOTH(cwA, ma, v2h);
    DOTH(n1B, mb, qh);  DOTH(cvB, mb, v1h);  DOTH(cwB, mb, v2h);
    const float p1A = tanh_pade(n1A*ra.x*s1);
    const float n2A = 0.5f*(n1A + cvA - mv1*ra.y);
    const float p2A = tanh_pade(n2A*ra.x*s2);
    const float p3A = tanh_pade(0.5f*(n2A + cwA - mv2*ra.y)*ra.x*s3);
    const float p1B = tanh_pade(n1B*rb.x*s1);
    const float n2B = 0.5f*(n1B + cvB - mv1*rb.y);
    const float p2B = tanh_pade(n2B*rb.x*s2);
    const float p3B = tanh_pade(0.5f*(n2B + cwB - mv2*rb.y)*rb.x*s3);
    const float eA = __expf(fmaf(p1A, cvA, p2A*cwA));
    const float eB = __expf(fmaf(p1B, cvB, p2B*cwB));
    const float SA = wave_sum64_all(eA);
    const float SB = wave_sum64_all(eB);
    const float wA = eA*__frcp_rn(SA) + p3A;
    const float wB = eB*__frcp_rn(SB) + p3B;
    ACCUM(acc, ma, wA);
    ACCUM(acc, mb, wB);
  }
  ST16(part + (((size_t)(q<<cshift) + ch)*64 + c)*16, acc);
}

// ---------------- R3: reduce -> squash -> out ----------------
__global__ __launch_bounds__(256) void reduce3_kernel(const float* __restrict__ part,
                                                      float* __restrict__ out,
                                                      int nchunk)
{
  const int tid = threadIdx.x;
  const int q = blockIdx.x*4 + (tid>>6), c = tid & 63;
  float hv[16];
  #pragma unroll
  for (int d=0;d<16;d++) hv[d]=0.f;
  const float* pp = part + ((size_t)q*nchunk*64 + c)*16;
  for (int ch=0; ch<nchunk; ch++, pp += 1024){
    float t[16]; LD16(t, pp);
    #pragma unroll
    for (int d=0;d<16;d++) hv[d]+=t[d];
  }
  float n2=0.f;
  #pragma unroll
  for (int d=0;d<16;d++) n2 += hv[d]*hv[d];
  const float sc = n2 / ((1.0f+n2)*sqrtf(n2+1e-8f));
  float o[16];
  #pragma unroll
  for (int d=0;d<16;d++) o[d] = hv[d]*sc;
  ST16(out + (size_t)q*CD + c*16, o);
}

extern "C" void kernel_launch(void* const* d_in, const int* in_sizes, int n_in,
                              void* d_out, int out_size, void* d_ws, size_t ws_size,
                              hipStream_t stream)
{
  const float* m  = (const float*)d_in[0];
  const float* q  = (const float*)d_in[1];
  const float* Ww = (const float*)d_in[2];
  const float* Wb = (const float*)d_in[3];
  float* out = (float*)d_out;

  // Workspace layout (bytes):
  //   hat  4,194,304 | rs 262,144 | hatH 1,048,576 | qhg 1,048,576 | s1g 131,072
  //   v1hg 1,048,576 | v2hg 1,048,576 | aux1 262,144 | aux2 262,144 | part nchunk*2 MB
  char* ws = (char*)d_ws;
  float*    hat  = (float*)   (ws + 0);
  float2*   rs   = (float2*)  (ws + 4194304);
  _Float16* hatH = (_Float16*)(ws + 4456448);
  float4*   qhg  = (float4*)  (ws + 5505024);
  float*    s1g  = (float*)   (ws + 6553600);
  float4*   v1hg = (float4*)  (ws + 6684672);
  float4*   v2hg = (float4*)  (ws + 7733248);
  float2*   aux1 = (float2*)  (ws + 8781824);
  float2*   aux2 = (float2*)  (ws + 9043968);
  float*    part = (float*)   (ws + 9306112);

  int nchunk = 16, cshift = 4;
  while (nchunk > 1 && 9306112ull + (size_t)nchunk*2097152ull > ws_size){ nchunk >>= 1; cshift--; }
  const int ilen = 512 / nchunk;
  const int pblocks = (QN*nchunk)/4;   // 4 waves/block, wave = (q, chunk)

  dim3 g0(16,16);
  gemm_hat<<<g0, 256, 0, stream>>>(m, q, Ww, Wb, hat, hatH);
  stats_kernel<<<256, 256, 0, stream>>>(hat, rs, qhg, s1g);
  pass1_kernel<<<pblocks, 256, 0, stream>>>((const float4*)hatH, rs, qhg, s1g, part, ilen, nchunk, cshift);
  reduce1_kernel<<<128, 256, 0, stream>>>(hat, part, v1hg, aux1, nchunk);
  pass2_kernel<<<pblocks, 256, 0, stream>>>((const float4*)hatH, rs, qhg, s1g, v1hg, aux1, part, ilen, nchunk, cshift);
  reduce2_kernel<<<128, 256, 0, stream>>>(hat, part, v1hg, v2hg, aux2, nchunk);
  pass3_kernel<<<pblocks, 256, 0, stream>>>((const float4*)hatH, rs, qhg, s1g, v1hg, v2hg, aux1, aux2, part, ilen, nchunk, cshift);
  reduce3_kernel<<<128, 256, 0, stream>>>(part, out, nchunk);
}

// Round 12
// 252.524 us; speedup vs baseline: 1.2594x; 1.0191x over previous
//
#include <hip/hip_runtime.h>
#include <math.h>

#define IN_CAPS 512
#define QN      512
#define IN_DIM  768
#define NCAPS   64
#define DCAPS   16
#define CD      1024   // NCAPS*DCAPS

typedef _Float16 half2_t __attribute__((ext_vector_type(2)));

#if __has_builtin(__builtin_amdgcn_rcpf)
  #define RCP(x) __builtin_amdgcn_rcpf(x)
#else
  #define RCP(x) __frcp_rn(x)
#endif

// tanh via continued-fraction Pade (|x|<=~1.05, err ~4e-6)
__device__ __forceinline__ float tanh_pade(float x){
  const float x2 = x*x;
  const float num = fmaf(x2, x2 + 105.0f, 945.0f);
  const float den = fmaf(x2, fmaf(x2, 15.0f, 420.0f), 945.0f);
  return x * num * RCP(den);
}

template<int CTRL>
__device__ __forceinline__ float dpp_add(float v){
  int r = __builtin_amdgcn_update_dpp(0, __float_as_int(v), CTRL, 0xF, 0xF, true);
  return v + __int_as_float(r);
}

// full 64-lane sum -> uniform scalar (pure DPP + readlane)
__device__ __forceinline__ float wave_sum64_all(float v){
  v = dpp_add<0xB1>(v);
  v = dpp_add<0x4E>(v);
  v = dpp_add<0x141>(v);
  v = dpp_add<0x140>(v);
  v = dpp_add<0x142>(v);
  v = dpp_add<0x143>(v);
  return __int_as_float(__builtin_amdgcn_readlane(__float_as_int(v), 63));
}

#define LD16(dst, ptr) { const float4* _p=(const float4*)(ptr); \
  float4 _a=_p[0], _b=_p[1], _c=_p[2], _d=_p[3]; \
  dst[0]=_a.x; dst[1]=_a.y; dst[2]=_a.z; dst[3]=_a.w; \
  dst[4]=_b.x; dst[5]=_b.y; dst[6]=_b.z; dst[7]=_b.w; \
  dst[8]=_c.x; dst[9]=_c.y; dst[10]=_c.z; dst[11]=_c.w; \
  dst[12]=_d.x; dst[13]=_d.y; dst[14]=_d.z; dst[15]=_d.w; }

#define ST16(ptr, src) { float4* _p=(float4*)(ptr); \
  _p[0]=make_float4(src[0],src[1],src[2],src[3]); \
  _p[1]=make_float4(src[4],src[5],src[6],src[7]); \
  _p[2]=make_float4(src[8],src[9],src[10],src[11]); \
  _p[3]=make_float4(src[12],src[13],src[14],src[15]); }

// load 8 packed half2 (32B) from 2 consecutive float4s
#define LDH(dst, ptrf4) { const float4* _p=(const float4*)(ptrf4); \
  float4 _a=_p[0], _b=_p[1]; \
  dst[0]=__builtin_bit_cast(half2_t,_a.x); dst[1]=__builtin_bit_cast(half2_t,_a.y); \
  dst[2]=__builtin_bit_cast(half2_t,_a.z); dst[3]=__builtin_bit_cast(half2_t,_a.w); \
  dst[4]=__builtin_bit_cast(half2_t,_b.x); dst[5]=__builtin_bit_cast(half2_t,_b.y); \
  dst[6]=__builtin_bit_cast(half2_t,_b.z); dst[7]=__builtin_bit_cast(half2_t,_b.w); }

// convert 8 half2 -> float[16]
#define CVT16(dst, h) { \
  _Pragma("unroll") for (int _j=0;_j<8;_j++){ \
    dst[2*_j]   = (float)h[_j].x; \
    dst[2*_j+1] = (float)h[_j].y; } }

// 2-way-split dot of two f32 16-vecs
#define DOT16(res, x, y) { float _e=0.f,_o=0.f; \
  _Pragma("unroll") for (int _d=0;_d<16;_d+=2){ _e = fmaf(x[_d],y[_d],_e); _o = fmaf(x[_d+1],y[_d+1],_o); } \
  res = _e+_o; }

// acc[16] += w * m[16]  (f32)
#define ACCUM(acc, m, w) { \
  _Pragma("unroll") for (int _d=0;_d<16;_d++) acc[_d] = fmaf(w, m[_d], acc[_d]); }

// centered hat_q fragment + rsqrt norm for lane's capsule
#define QPROLOGUE() \
  float qcc1[16]; float s1; { \
    float qc_[16]; \
    LD16(qc_, hat + (size_t)(IN_CAPS + q)*CD + c*16); \
    float s_=0.f; \
    _Pragma("unroll") for (int d=0;d<16;d++) s_ += qc_[d]; \
    const float mean_ = s_*(1.0f/16.0f); \
    float n2_=0.f; \
    _Pragma("unroll") for (int d=0;d<16;d++){ qcc1[d]=qc_[d]-mean_; n2_ += qcc1[d]*qcc1[d]; } \
    s1 = __frsqrt_rn(n2_ + 1e-12f); }

// decode: wave -> (q, chunk); lane = capsule
#define WDECODE() \
  const int tid = threadIdx.x; \
  const int gw  = blockIdx.x*4 + (tid >> 6); \
  const int q   = gw >> cshift; \
  const int ch  = gw & (nch-1); \
  const int c   = tid & 63;

// ---------------- K0: hat = [m;q] @ W_w + W_b (+ f16 copy of m-rows) ----------------
__global__ __launch_bounds__(256) void gemm_hat(const float* __restrict__ m,
                                                const float* __restrict__ q,
                                                const float* __restrict__ Ww,
                                                const float* __restrict__ Wb,
                                                float* __restrict__ hat,
                                                _Float16* __restrict__ hatH)
{
  __shared__ float As[16][65];
  __shared__ float Bs[16][65];
  const int tid = threadIdx.x;
  const int bm = blockIdx.y, bn = blockIdx.x;
  const int tx = tid & 15, ty = tid >> 4;

  float acc[4][4];
  #pragma unroll
  for (int a=0;a<4;a++)
    #pragma unroll
    for (int b=0;b<4;b++) acc[a][b]=0.0f;

  const int r  = tid >> 2;
  const int kk = (tid & 3) << 2;
  const int row = bm*64 + r;
  const float* srcA = (row < IN_CAPS) ? (m + row*IN_DIM) : (q + (row-IN_CAPS)*IN_DIM);
  const int krow = tid >> 4;
  const int cc   = (tid & 15) << 2;

  for (int k0=0; k0<IN_DIM; k0+=16){
    float4 av = *(const float4*)(srcA + k0 + kk);
    As[kk+0][r]=av.x; As[kk+1][r]=av.y; As[kk+2][r]=av.z; As[kk+3][r]=av.w;
    float4 bv = *(const float4*)(Ww + (size_t)(k0+krow)*CD + bn*64 + cc);
    Bs[krow][cc+0]=bv.x; Bs[krow][cc+1]=bv.y; Bs[krow][cc+2]=bv.z; Bs[krow][cc+3]=bv.w;
    __syncthreads();
    #pragma unroll
    for (int k=0;k<16;k++){
      float a[4], b[4];
      #pragma unroll
      for (int j=0;j<4;j++) a[j] = As[k][ty*4+j];
      #pragma unroll
      for (int j=0;j<4;j++) b[j] = Bs[k][tx*4+j];
      #pragma unroll
      for (int ii=0;ii<4;ii++)
        #pragma unroll
        for (int jj=0;jj<4;jj++) acc[ii][jj] += a[ii]*b[jj];
    }
    __syncthreads();
  }
  const int col0 = bn*64 + tx*4;
  #pragma unroll
  for (int ii=0;ii<4;ii++){
    const int orow = bm*64 + ty*4 + ii;
    float v[4];
    #pragma unroll
    for (int jj=0;jj<4;jj++) v[jj] = acc[ii][jj] + Wb[col0+jj];
    #pragma unroll
    for (int jj=0;jj<4;jj++) hat[(size_t)orow*CD + col0 + jj] = v[jj];
    if (orow < IN_CAPS){
      half2_t h0, h1;
      h0.x=(_Float16)v[0]; h0.y=(_Float16)v[1];
      h1.x=(_Float16)v[2]; h1.y=(_Float16)v[3];
      float2 pk = make_float2(__builtin_bit_cast(float,h0), __builtin_bit_cast(float,h1));
      *(float2*)(hatH + (size_t)orow*CD + col0) = pk;
    }
  }
}

// ---------------- K1: per-(i,c) stats: rs = (rsqrt(||m-mean||^2), sum_d m) ----------------
__global__ __launch_bounds__(256) void stats_kernel(const float* __restrict__ hat,
                                                    float2* __restrict__ rs)
{
  const int t = blockIdx.x*256 + threadIdx.x;   // 0..32767
  const int i = t >> 6, c = t & 63;
  float v[16];
  LD16(v, hat + (size_t)i*CD + c*16);
  float s=0.f;
  #pragma unroll
  for (int d=0;d<16;d++) s += v[d];
  const float mean = s*(1.0f/16.0f);
  float n2=0.f;
  #pragma unroll
  for (int d=0;d<16;d++){ float x=v[d]-mean; n2+=x*x; }
  rs[t] = make_float2(__frsqrt_rn(n2 + 1e-12f), s);
}

// ---------------- P1 ----------------
__global__ __launch_bounds__(256) void pass1_kernel(const float4* __restrict__ hatH4,
                                                    const float* __restrict__ hat,
                                                    const float2* __restrict__ rs_g,
                                                    float* __restrict__ part,
                                                    int ilen, int nch, int cshift)
{
  WDECODE();
  QPROLOGUE();

  float acc[16];
  #pragma unroll
  for (int d=0;d<16;d++) acc[d]=0.f;

  const int i0 = ch*ilen;
  const float4* mp = hatH4 + (size_t)i0*128 + c*2;
  const float2* rp = rs_g + i0*64 + c;
  for (int i=0;i<ilen;i+=2, mp+=256, rp+=128){
    half2_t ha[8], hb[8];
    LDH(ha, mp); LDH(hb, mp+128);
    float ma[16], mb[16];
    CVT16(ma, ha); CVT16(mb, hb);
    const float ra = rp[0].x, rb = rp[64].x;
    float nA, nB;
    DOT16(nA, ma, qcc1);
    DOT16(nB, mb, qcc1);
    const float wA = 0.015625f + tanh_pade(nA*ra*s1);
    const float wB = 0.015625f + tanh_pade(nB*rb*s1);
    ACCUM(acc, ma, wA);
    ACCUM(acc, mb, wB);
  }
  ST16(part + (((size_t)(q<<cshift) + ch)*64 + c)*16, acc);
}

// ---------------- R1: reduce -> v1 (f32) + aux1=(s2, mv1) ----------------
__global__ __launch_bounds__(256) void reduce1_kernel(const float* __restrict__ hat,
                                                      const float* __restrict__ part,
                                                      float* __restrict__ v1g,
                                                      float2* __restrict__ aux1,
                                                      int nchunk)
{
  const int tid = threadIdx.x;
  const int q = blockIdx.x*4 + (tid>>6), c = tid & 63;
  float hv[16];
  #pragma unroll
  for (int d=0;d<16;d++) hv[d]=0.f;
  const float* pp = part + ((size_t)q*nchunk*64 + c)*16;
  for (int ch=0; ch<nchunk; ch++, pp += 1024){
    float t[16]; LD16(t, pp);
    #pragma unroll
    for (int d=0;d<16;d++) hv[d]+=t[d];
  }
  float n2=0.f;
  #pragma unroll
  for (int d=0;d<16;d++) n2 += hv[d]*hv[d];
  const float sc = n2 / ((1.0f+n2)*sqrtf(n2+1e-8f));
  float v1[16]; float sv=0.f;
  #pragma unroll
  for (int d=0;d<16;d++){ v1[d]=hv[d]*sc; sv+=v1[d]; }
  ST16(v1g + ((size_t)q*64 + c)*16, v1);
  float qc[16]; LD16(qc, hat + (size_t)(IN_CAPS+q)*CD + c*16);
  float s=0.f, ss=0.f;
  #pragma unroll
  for (int d=0;d<16;d++){ const float t2 = 0.5f*(qc[d]+v1[d]); s+=t2; ss+=t2*t2; }
  const float mean = s*(1.0f/16.0f);
  aux1[q*64+c] = make_float2(__frsqrt_rn(ss - 16.0f*mean*mean + 1e-12f), sv*(1.0f/16.0f));
}

// ---------------- P2 ----------------
__global__ __launch_bounds__(256) void pass2_kernel(const float4* __restrict__ hatH4,
                                                    const float* __restrict__ hat,
                                                    const float2* __restrict__ rs_g,
                                                    const float* __restrict__ v1g,
                                                    const float2* __restrict__ aux1,
                                                    float* __restrict__ part,
                                                    int ilen, int nch, int cshift)
{
  WDECODE();
  QPROLOGUE();
  float v1[16];
  LD16(v1, v1g + ((size_t)q*64 + c)*16);
  const float2 a1 = aux1[q*64+c];
  const float s2 = a1.x, mv1 = a1.y;

  float acc[16];
  #pragma unroll
  for (int d=0;d<16;d++) acc[d]=0.f;

  const int i0 = ch*ilen;
  const float4* mp = hatH4 + (size_t)i0*128 + c*2;
  const float2* rp = rs_g + i0*64 + c;
  for (int i=0;i<ilen;i+=2, mp+=256, rp+=128){
    half2_t ha[8], hb[8];
    LDH(ha, mp); LDH(hb, mp+128);
    float ma[16], mb[16];
    CVT16(ma, ha); CVT16(mb, hb);
    const float2 ra = rp[0], rb = rp[64];
    float n1A, cvA, n1B, cvB;
    DOT16(n1A, ma, qcc1); DOT16(cvA, ma, v1);
    DOT16(n1B, mb, qcc1); DOT16(cvB, mb, v1);
    const float p1A = tanh_pade(n1A*ra.x*s1);
    const float p2A = tanh_pade(0.5f*(n1A + cvA - mv1*ra.y)*ra.x*s2);
    const float p1B = tanh_pade(n1B*rb.x*s1);
    const float p2B = tanh_pade(0.5f*(n1B + cvB - mv1*rb.y)*rb.x*s2);
    const float eA = __expf(p1A*cvA);
    const float eB = __expf(p1B*cvB);
    const float SA = wave_sum64_all(eA);
    const float SB = wave_sum64_all(eB);
    const float wA = eA*RCP(SA) + p2A;
    const float wB = eB*RCP(SB) + p2B;
    ACCUM(acc, ma, wA);
    ACCUM(acc, mb, wB);
  }
  ST16(part + (((size_t)(q<<cshift) + ch)*64 + c)*16, acc);
}

// ---------------- R2: reduce -> v2 (f32) + aux2=(s3, mv2) ----------------
__global__ __launch_bounds__(256) void reduce2_kernel(const float* __restrict__ hat,
                                                      const float* __restrict__ part,
                                                      const float* __restrict__ v1g,
                                                      float* __restrict__ v2g,
                                                      float2* __restrict__ aux2,
                                                      int nchunk)
{
  const int tid = threadIdx.x;
  const int q = blockIdx.x*4 + (tid>>6), c = tid & 63;
  float hv[16];
  #pragma unroll
  for (int d=0;d<16;d++) hv[d]=0.f;
  const float* pp = part + ((size_t)q*nchunk*64 + c)*16;
  for (int ch=0; ch<nchunk; ch++, pp += 1024){
    float t[16]; LD16(t, pp);
    #pragma unroll
    for (int d=0;d<16;d++) hv[d]+=t[d];
  }
  float n2=0.f;
  #pragma unroll
  for (int d=0;d<16;d++) n2 += hv[d]*hv[d];
  const float sc = n2 / ((1.0f+n2)*sqrtf(n2+1e-8f));
  float v2[16]; float sv=0.f;
  #pragma unroll
  for (int d=0;d<16;d++){ v2[d]=hv[d]*sc; sv+=v2[d]; }
  ST16(v2g + ((size_t)q*64 + c)*16, v2);
  float qc[16];  LD16(qc, hat + (size_t)(IN_CAPS+q)*CD + c*16);
  float v1[16];  LD16(v1, v1g + ((size_t)q*64 + c)*16);
  float s=0.f, ss=0.f;
  #pragma unroll
  for (int d=0;d<16;d++){
    const float t3 = 0.25f*qc[d] + 0.25f*v1[d] + 0.5f*v2[d];   // q_cur3
    s+=t3; ss+=t3*t3;
  }
  const float mean = s*(1.0f/16.0f);
  aux2[q*64+c] = make_float2(__frsqrt_rn(ss - 16.0f*mean*mean + 1e-12f), sv*(1.0f/16.0f));
}

// ---------------- P3 ----------------
__global__ __launch_bounds__(256) void pass3_kernel(const float4* __restrict__ hatH4,
                                                    const float* __restrict__ hat,
                                                    const float2* __restrict__ rs_g,
                                                    const float* __restrict__ v1g,
                                                    const float* __restrict__ v2g,
                                                    const float2* __restrict__ aux1,
                                                    const float2* __restrict__ aux2,
                                                    float* __restrict__ part,
                                                    int ilen, int nch, int cshift)
{
  WDECODE();
  QPROLOGUE();
  float v1[16], v2[16];
  LD16(v1, v1g + ((size_t)q*64 + c)*16);
  LD16(v2, v2g + ((size_t)q*64 + c)*16);
  const float2 a1 = aux1[q*64+c];
  const float2 a2 = aux2[q*64+c];
  const float s2 = a1.x, mv1 = a1.y, s3 = a2.x, mv2 = a2.y;

  float acc[16];
  #pragma unroll
  for (int d=0;d<16;d++) acc[d]=0.f;

  const int i0 = ch*ilen;
  const float4* mp = hatH4 + (size_t)i0*128 + c*2;
  const float2* rp = rs_g + i0*64 + c;
  for (int i=0;i<ilen;i+=2, mp+=256, rp+=128){
    half2_t ha[8], hb[8];
    LDH(ha, mp); LDH(hb, mp+128);
    float ma[16], mb[16];
    CVT16(ma, ha); CVT16(mb, hb);
    const float2 ra = rp[0], rb = rp[64];
    float n1A, cvA, cwA, n1B, cvB, cwB;
    DOT16(n1A, ma, qcc1); DOT16(cvA, ma, v1); DOT16(cwA, ma, v2);
    DOT16(n1B, mb, qcc1); DOT16(cvB, mb, v1); DOT16(cwB, mb, v2);
    const float p1A = tanh_pade(n1A*ra.x*s1);
    const float n2A = 0.5f*(n1A + cvA - mv1*ra.y);
    const float p2A = tanh_pade(n2A*ra.x*s2);
    const float p3A = tanh_pade(0.5f*(n2A + cwA - mv2*ra.y)*ra.x*s3);
    const float p1B = tanh_pade(n1B*rb.x*s1);
    const float n2B = 0.5f*(n1B + cvB - mv1*rb.y);
    const float p2B = tanh_pade(n2B*rb.x*s2);
    const float p3B = tanh_pade(0.5f*(n2B + cwB - mv2*rb.y)*rb.x*s3);
    const float eA = __expf(fmaf(p1A, cvA, p2A*cwA));
    const float eB = __expf(fmaf(p1B, cvB, p2B*cwB));
    const float SA = wave_sum64_all(eA);
    const float SB = wave_sum64_all(eB);
    const float wA = eA*RCP(SA) + p3A;
    const float wB = eB*RCP(SB) + p3B;
    ACCUM(acc, ma, wA);
    ACCUM(acc, mb, wB);
  }
  ST16(part + (((size_t)(q<<cshift) + ch)*64 + c)*16, acc);
}

// ---------------- R3: reduce -> squash -> out ----------------
__global__ __launch_bounds__(256) void reduce3_kernel(const float* __restrict__ part,
                                                      float* __restrict__ out,
                                                      int nchunk)
{
  const int tid = threadIdx.x;
  const int q = blockIdx.x*4 + (tid>>6), c = tid & 63;
  float hv[16];
  #pragma unroll
  for (int d=0;d<16;d++) hv[d]=0.f;
  const float* pp = part + ((size_t)q*nchunk*64 + c)*16;
  for (int ch=0; ch<nchunk; ch++, pp += 1024){
    float t[16]; LD16(t, pp);
    #pragma unroll
    for (int d=0;d<16;d++) hv[d]+=t[d];
  }
  float n2=0.f;
  #pragma unroll
  for (int d=0;d<16;d++) n2 += hv[d]*hv[d];
  const float sc = n2 / ((1.0f+n2)*sqrtf(n2+1e-8f));
  float o[16];
  #pragma unroll
  for (int d=0;d<16;d++) o[d] = hv[d]*sc;
  ST16(out + (size_t)q*CD + c*16, o);
}

extern "C" void kernel_launch(void* const* d_in, const int* in_sizes, int n_in,
                              void* d_out, int out_size, void* d_ws, size_t ws_size,
                              hipStream_t stream)
{
  const float* m  = (const float*)d_in[0];
  const float* q  = (const float*)d_in[1];
  const float* Ww = (const float*)d_in[2];
  const float* Wb = (const float*)d_in[3];
  float* out = (float*)d_out;

  // Workspace layout (bytes):
  //   hat  4,194,304 | rs 262,144 | hatH 1,048,576 | v1g 2,097,152 | v2g 2,097,152
  //   aux1 262,144 | aux2 262,144 | part nchunk*2,097,152
  char* ws = (char*)d_ws;
  float*    hat  = (float*)   (ws + 0);
  float2*   rs   = (float2*)  (ws + 4194304);
  _Float16* hatH = (_Float16*)(ws + 4456448);
  float*    v1g  = (float*)   (ws + 5505024);
  float*    v2g  = (float*)   (ws + 7602176);
  float2*   aux1 = (float2*)  (ws + 9699328);
  float2*   aux2 = (float2*)  (ws + 9961472);
  float*    part = (float*)   (ws + 10223616);

  int nchunk = 16, cshift = 4;
  while (nchunk > 1 && 10223616ull + (size_t)nchunk*2097152ull > ws_size){ nchunk >>= 1; cshift--; }
  const int ilen = 512 / nchunk;
  const int pblocks = (QN*nchunk)/4;   // 4 waves/block, wave = (q, chunk)

  dim3 g0(16,16);
  gemm_hat<<<g0, 256, 0, stream>>>(m, q, Ww, Wb, hat, hatH);
  stats_kernel<<<128, 256, 0, stream>>>(hat, rs);
  pass1_kernel<<<pblocks, 256, 0, stream>>>((const float4*)hatH, hat, rs, part, ilen, nchunk, cshift);
  reduce1_kernel<<<128, 256, 0, stream>>>(hat, part, v1g, aux1, nchunk);
  pass2_kernel<<<pblocks, 256, 0, stream>>>((const float4*)hatH, hat, rs, v1g, aux1, part, ilen, nchunk, cshift);
  reduce2_kernel<<<128, 256, 0, stream>>>(hat, part, v1g, v2g, aux2, nchunk);
  pass3_kernel<<<pblocks, 256, 0, stream>>>((const float4*)hatH, hat, rs, v1g, v2g, aux1, aux2, part, ilen, nchunk, cshift);
  reduce3_kernel<<<128, 256, 0, stream>>>(part, out, nchunk);
}